// Round 6
// baseline (640.634 us; speedup 1.0000x reference)
//
#include <hip/hip_runtime.h>
#include <hip/hip_bf16.h>
#include <math.h>

// Problem constants
#define NB   16      // batch
#define CC   64      // channels
#define ICH  32      // inter channels
#define TV   1600    // T*V = 64*25
#define NTV  (NB*TV) // 25600
#define NBLK 800     // persistent grid: 800 blocks

typedef __bf16 bf16x8 __attribute__((ext_vector_type(8)));
typedef __bf16 bf16x4 __attribute__((ext_vector_type(4)));
typedef float  f32x4  __attribute__((ext_vector_type(4)));

struct Args {
  const float *x, *Wv, *bv, *Wk, *bk, *Wq, *bq, *Wt, *bt, *gamma, *beta,
              *W1, *b1, *W2, *b2;
  __bf16 *Qb, *Kb, *VTb, *Pb;
  float *GSP, *AVG, *out;
  unsigned *bar;     // [2] single-use barrier counters, memset to 0 per launch
};

// ---------------------------------------------------------------------------
// Hand-rolled grid barrier (capture-safe replacement for grid.sync()).
// DEADLOCK-FREE ONLY IF ALL NBLK BLOCKS ARE CO-RESIDENT: enforced by
// __launch_bounds__(256, 4) on mega_kernel (VGPR cap 128 -> 4 blocks/CU ->
// 1024 >= 800; LDS 31,744 B -> 5/CU not binding). Round-5 hang post-mortem:
// without the cap the merged kernel exceeded 128 VGPR -> 2 blocks/CU ->
// 512 < 800 -> spin deadlock.
// ---------------------------------------------------------------------------
__device__ __forceinline__ void grid_barrier(unsigned* cnt) {
  __syncthreads();                      // all block work done
  if (threadIdx.x == 0) {
    __threadfence();                    // release: prior writes -> device scope
    unsigned arrived = __hip_atomic_fetch_add(cnt, 1u, __ATOMIC_ACQ_REL,
                                              __HIP_MEMORY_SCOPE_AGENT);
    if (arrived + 1u < (unsigned)NBLK) {
      while (__hip_atomic_load(cnt, __ATOMIC_ACQUIRE,
                               __HIP_MEMORY_SCOPE_AGENT) < (unsigned)NBLK)
        __builtin_amdgcn_s_sleep(1);
    }
    __threadfence();                    // acquire: invalidate stale caches
  }
  __syncthreads();                      // whole block released together
}

// ---------------------------------------------------------------------------
// Phase 1 unit: 1x1 conv projections (12-way p-split per tile) + ChannelGate
// means. Unit space 0..1311 (proj 0..1247 w/ 48 no-ops, gate 1248..1311).
// Grid-strided over 800 blocks; u%8 == blockIdx%8 for both rounds, so the
// XCD swizzle (all 12 subs of an x-tile on one XCD residue) is preserved.
//  Qb = k_x [N,TV,32] (PRE-SCALED by log2e)  Kb = q_x  VTb = v_x^T
// ---------------------------------------------------------------------------
__device__ void proj_gate_unit(const Args& a, int u) {
  if (u >= 1248) {
    // ---- ChannelGate phase 1: per-(n, c) mean over TV ----
    int b = u - 1248;
    int n = b >> 2, cq = b & 3;
    int c16 = threadIdx.x >> 4, l = threadIdx.x & 15;
    int c = cq * 16 + c16;
    const float4* xp = (const float4*)(a.x + ((size_t)n * CC + c) * TV) + l;
    float s = 0.f;
#pragma unroll
    for (int i = 0; i < 25; ++i) {
      float4 v = xp[i * 16];
      s += v.x + v.y + v.z + v.w;
    }
#pragma unroll
    for (int off = 8; off >= 1; off >>= 1) s += __shfl_down(s, off, 16);
    if (l == 0) a.AVG[n * CC + c] = s * (1.0f / (float)TV);
    return;
  }

  int r = u & 7;
  int i = u >> 3;                        // 0..155
  int g = i / 12, sub = i % 12;          // sub = p*4 + og
  int tile = r + 8 * g;
  if (tile >= 100) return;               // 48 no-op units

  int p = sub >> 2, og = sub & 3;
  int ob = og * 8;
  int tvIdx = tile * 256 + threadIdx.x;  // 0..25599
  int n = tvIdx / TV, tv = tvIdx % TV;

  const float* W; const float* B;
  if (p == 0)      { W = a.Wv; B = a.bv; }
  else if (p == 1) { W = a.Wk; B = a.bk; }
  else             { W = a.Wq; B = a.bq; }

  float acc[8];
#pragma unroll
  for (int j = 0; j < 8; ++j) acc[j] = B[ob + j];

  const float* xp = a.x + (size_t)n * CC * TV + tv;
#pragma unroll 16
  for (int c = 0; c < CC; ++c) {
    float xc = xp[c * TV];
#pragma unroll
    for (int j = 0; j < 8; ++j)
      acc[j] = fmaf(W[(ob + j) * CC + c], xc, acc[j]);
  }

  if (p == 0) {                           // v_x -> transposed
#pragma unroll
    for (int j = 0; j < 8; ++j)
      a.VTb[(n * ICH + ob + j) * TV + tv] = (__bf16)acc[j];
  } else {
    if (p == 1) {                         // fold log2(e): attn uses v_exp_f32
#pragma unroll
      for (int j = 0; j < 8; ++j)
        acc[j] *= 1.4426950408889634f;
    }
    bf16x8 t;
#pragma unroll
    for (int j = 0; j < 8; ++j) t[j] = (__bf16)acc[j];
    int base = (n * TV + tv) * ICH + ob;
    if (p == 1) *(bf16x8*)(a.Qb + base) = t;   // k_x -> attention rows
    else        *(bf16x8*)(a.Kb + base) = t;   // q_x -> attention cols
  }
}

// ---------------------------------------------------------------------------
// Phase 2 unit: MFMA flash attention (swapped QK^T -> packed ds_write_b64,
// exp2 in log2-domain, K+V register pipelining) + fused BN-stats epilogue.
// BN partials written COLUMN-MAJOR: GSP[c*800 + u]. 1:1 with the 800 blocks.
// ---------------------------------------------------------------------------
__device__ void attn_unit(const Args& a, int b, float* smem_f) {
  int r8 = b & 7, qq = b >> 3;               // qq in [0,100)
  int n = r8 * 2 + (qq >= 50 ? 1 : 0);
  int rowTile = (qq >= 50) ? qq - 50 : qq;
  int row0 = rowTile * 32;

  int w = threadIdx.x >> 6;
  int lane = threadIdx.x & 63;
  int m = lane & 15, q = lane >> 4;

  // main-loop Pbuf: per wave 2 tiles x 16 x 72 bf16 = 2304 elem (4608 B)
  __bf16* Pw = (__bf16*)smem_f + w * 2304;

  const __bf16* Qn = a.Qb  + (size_t)n * TV * ICH;
  const __bf16* Kn = a.Kb  + (size_t)n * TV * ICH;
  const __bf16* Vn = a.VTb + (size_t)n * ICH * TV;

  bf16x8 aQ0 = *(const bf16x8*)(Qn + (row0 + m) * ICH + q * 8);
  bf16x8 aQ1 = *(const bf16x8*)(Qn + (row0 + 16 + m) * ICH + q * 8);

  f32x4 o00 = {0.f,0.f,0.f,0.f}, o01 = {0.f,0.f,0.f,0.f};
  f32x4 o10 = {0.f,0.f,0.f,0.f}, o11 = {0.f,0.f,0.f,0.f};
  float ls0 = 0.f, ls1 = 0.f;                // lane-local rowsum (row = m)
  const f32x4 zero = {0.f,0.f,0.f,0.f};

  // chunk offset for this wave, rotated per block so the extra (7th) chunk
  // (offset 0) moves between waves across blocks.
  int ow = (w + b) & 3;                      // offset residue; 0 -> 7 chunks
  int nch = (ow == 0) ? 7 : 6;

  // preload chunk 0's K fragments into registers
  bf16x8 bKc[4];
  {
    int s0 = ow * 64;
#pragma unroll
    for (int st = 0; st < 4; ++st)
      bKc[st] = *(const bf16x8*)(Kn + (s0 + st * 16 + m) * ICH + q * 8);
  }

  for (int j = 0; j < nch; ++j) {
    int s0 = (4 * j + ow) * 64;
    // ---- swapped QK^T: C = P^T tile, lane (q,m): col=m (attn row),
    //      rows = s-offset st*16 + q*4 + r (4 consecutive s per lane) ----
#pragma unroll
    for (int st = 0; st < 4; ++st) {
      f32x4 a0 = __builtin_amdgcn_mfma_f32_16x16x32_bf16(bKc[st], aQ0, zero, 0, 0, 0);
      f32x4 a1 = __builtin_amdgcn_mfma_f32_16x16x32_bf16(bKc[st], aQ1, zero, 0, 0, 0);
      bf16x4 t0, t1;
#pragma unroll
      for (int r = 0; r < 4; ++r) {
        float e0 = __builtin_amdgcn_exp2f(a0[r]); ls0 += e0; t0[r] = (__bf16)e0;
        float e1 = __builtin_amdgcn_exp2f(a1[r]); ls1 += e1; t1[r] = (__bf16)e1;
      }
      int off = m * 72 + st * 16 + q * 4;    // byte off m*144+st*32+q*8: 8B-aligned
      *(bf16x4*)(Pw + off)        = t0;      // one ds_write_b64 per st/tile
      *(bf16x4*)(Pw + 1152 + off) = t1;
    }
    // prefetch next chunk's K + this chunk's V BEFORE the wait
    int chn = 4 * (j + 1) + ow;
    int s0n = (chn < 25 ? chn : 0) * 64;       // clamped, wave-uniform
    bf16x8 bKn[4], pV[2][2];
#pragma unroll
    for (int st = 0; st < 4; ++st)
      bKn[st] = *(const bf16x8*)(Kn + (s0n + st * 16 + m) * ICH + q * 8);
#pragma unroll
    for (int kc = 0; kc < 2; ++kc)
#pragma unroll
      for (int ict = 0; ict < 2; ++ict)
        pV[kc][ict] = *(const bf16x8*)(Vn + (ict * 16 + m) * TV + s0 + kc * 32 + q * 8);
    // in-wave DS write->read ordering
    asm volatile("s_waitcnt lgkmcnt(0)" ::: "memory");
    // ---- P*V: 2 k-chunks of 32 s ----
#pragma unroll
    for (int kc = 0; kc < 2; ++kc) {
      bf16x8 aP0 = *(const bf16x8*)(Pw + m * 72 + kc * 32 + q * 8);
      bf16x8 aP1 = *(const bf16x8*)(Pw + 1152 + m * 72 + kc * 32 + q * 8);
      o00 = __builtin_amdgcn_mfma_f32_16x16x32_bf16(aP0, pV[kc][0], o00, 0, 0, 0);
      o10 = __builtin_amdgcn_mfma_f32_16x16x32_bf16(aP1, pV[kc][0], o10, 0, 0, 0);
      o01 = __builtin_amdgcn_mfma_f32_16x16x32_bf16(aP0, pV[kc][1], o01, 0, 0, 0);
      o11 = __builtin_amdgcn_mfma_f32_16x16x32_bf16(aP1, pV[kc][1], o11, 0, 0, 0);
    }
#pragma unroll
    for (int st = 0; st < 4; ++st) bKc[st] = bKn[st];
  }

  // row sums: lane (q,m) has the partial for row m over its q-subset of s;
  // sum the 4 q-lanes, then gather into the merge layout (row = q*4+r).
  ls0 += __shfl_xor(ls0, 16, 64); ls0 += __shfl_xor(ls0, 32, 64);
  ls1 += __shfl_xor(ls1, 16, 64); ls1 += __shfl_xor(ls1, 32, 64);
  f32x4 lv0, lv1;
#pragma unroll
  for (int r = 0; r < 4; ++r) {
    int src = q * 4 + r;                    // lane src (q=0 group) holds row src
    lv0[r] = __shfl(ls0, src, 64);
    lv1[r] = __shfl(ls1, src, 64);
  }

  // ---- epilogue arena (aliases Pbuf, which is dead after the barrier) ----
  float* pub = smem_f;                       // [4 waves][64 lanes][24]
  float* Pl  = smem_f + 6144;                // [32][36] normalized P tile
  float* red = smem_f + 7296;                // [4 waves][128]

  __syncthreads();
  f32x4* mp = (f32x4*)(pub + (w * 64 + lane) * 24);
  mp[0] = o00; mp[1] = o01; mp[2] = o10; mp[3] = o11;
  mp[4] = lv0; mp[5] = lv1;
  __syncthreads();

  // parallel merge: wave w owns group w; ls0 for w<2, ls1 for w>=2.
  {
    int lsIdx = 4 + (w >> 1);
    const f32x4* p0 = (const f32x4*)(pub + lane * 24);
    f32x4 osum = p0[w];
    f32x4 lsum = p0[lsIdx];
#pragma unroll
    for (int ww = 1; ww < 4; ++ww) {
      const f32x4* pp = (const f32x4*)(pub + (ww * 64 + lane) * 24);
      f32x4 ov = pp[w], lv = pp[lsIdx];
#pragma unroll
      for (int r = 0; r < 4; ++r) { osum[r] += ov[r]; lsum[r] += lv[r]; }
    }
    int tile = w >> 1, colh = (w & 1) * 16;
#pragma unroll
    for (int r = 0; r < 4; ++r) {
      float p = osum[r] / lsum[r];
      int row = tile * 16 + q * 4 + r;
      a.Pb[(n * TV + row0 + row) * ICH + colh + m] = (__bf16)p;
      Pl[row * 36 + colh + m] = p;
    }
  }
  __syncthreads();

  // ---- fused BN stats: thread (c = t&63, rows w*8..w*8+7) 64ch dot.
  // Pl reads are wave-uniform b128 broadcasts (stride 36 -> 16B-aligned).
  int c = threadIdx.x & 63;
  float wr[ICH];
#pragma unroll
  for (int i = 0; i < ICH; ++i) wr[i] = a.Wt[c * ICH + i];
  float bc = a.bt[c];
  float sy = 0.f, sy2 = 0.f;
#pragma unroll
  for (int rr = 0; rr < 8; ++rr) {
    const f32x4* pr = (const f32x4*)(Pl + (w * 8 + rr) * 36);
    float y = bc;
#pragma unroll
    for (int u = 0; u < 8; ++u) {
      f32x4 pv = pr[u];
#pragma unroll
      for (int k = 0; k < 4; ++k) y = fmaf(wr[u * 4 + k], pv[k], y);
    }
    sy += y; sy2 += y * y;
  }
  red[w * 128 + c]      = sy;
  red[w * 128 + 64 + c] = sy2;
  __syncthreads();
  if (threadIdx.x < 128) {
    int t = threadIdx.x;
    float s = red[t] + red[128 + t] + red[256 + t] + red[384 + t];
    a.GSP[(size_t)t * 800 + b] = s;          // COLUMN-MAJOR: consumer-contiguous
  }
}

// ---------------------------------------------------------------------------
// Phase 3 unit: fused finalize + apply. Redundantly recomputes the 16 BN-stat
// column sums for its 8 channels (column-major GSP -> coalesced 64 B runs)
// + ChannelGate MLP, then recomputes y from bf16 P and applies BN + gate +
// residual. Unit space 0..831 (32 no-ops), grid-strided over 800 blocks.
// ---------------------------------------------------------------------------
__device__ void apply_unit(const Args& a, int u, float* smem_f) {
  int r = u & 7;
  int i = u >> 3;                       // 0..103
  int cg = i & 7, h = i >> 3;           // h in 0..12
  int tb = r + 8 * h;
  if (tb >= 100) return;                // no-op units

  int tvIdx = tb * 256 + threadIdx.x;
  int n = tvIdx / TV, tv = tvIdx % TV;

  float* sstat = smem_f;                // [16]: 0..7 sum y, 8..15 sum y^2
  float* sSS   = smem_f + 16;           // [16]: 0..7 scale, 8..15 shift
  float* sG    = smem_f + 32;           // [8]: gate for (n, cg*8..cg*8+7)

  // ---- Phase A: 16 threads/column sum 50 slots each ----
  {
    int colid = threadIdx.x >> 4;       // 0..15
    int sub = threadIdx.x & 15;         // 0..15
    int c8 = colid & 7;
    int gc = (colid < 8) ? (cg * 8 + c8) : (64 + cg * 8 + c8);
    const float* gp = a.GSP + (size_t)gc * 800;
    float s = 0.f;
#pragma unroll
    for (int k = 0; k < 50; ++k) s += gp[sub + k * 16];
#pragma unroll
    for (int off = 8; off >= 1; off >>= 1) s += __shfl_down(s, off, 16);
    if (sub == 0) sstat[colid] = s;
  }
  __syncthreads();
  if (threadIdx.x < 8) {
    int c8 = threadIdx.x;
    int c = cg * 8 + c8;
    float mean = sstat[c8] * (1.f / (float)NTV);
    float var  = sstat[8 + c8] * (1.f / (float)NTV) - mean * mean;
    float scale = rsqrtf(var + 1e-5f) * a.gamma[c];
    sSS[c8] = scale;
    sSS[8 + c8] = a.beta[c] - mean * scale;
    // ChannelGate MLP for this n (redundant across the 8 lanes, tiny)
    float hh[4];
#pragma unroll
    for (int jj = 0; jj < 4; ++jj) {
      float hv = a.b1[jj];
      for (int c2 = 0; c2 < CC; ++c2)
        hv = fmaf(a.W1[jj * CC + c2], a.AVG[n * CC + c2], hv);
      hh[jj] = fmaxf(hv, 0.f);
    }
    float g = a.b2[c];
#pragma unroll
    for (int jj = 0; jj < 4; ++jj) g = fmaf(a.W2[c * 4 + jj], hh[jj], g);
    sG[c8] = 1.f / (1.f + __expf(-g));
  }
  __syncthreads();

  // ---- Phase B: recompute y for 8 channels from bf16 P, apply ----
  float f[ICH];
  const bf16x8* pp = (const bf16x8*)(a.Pb + ((size_t)(n * TV + tv)) * ICH);
#pragma unroll
  for (int uu = 0; uu < 4; ++uu) {
    bf16x8 v = pp[uu];
#pragma unroll
    for (int j = 0; j < 8; ++j) f[uu * 8 + j] = (float)v[j];
  }

#pragma unroll
  for (int j = 0; j < 8; ++j) {
    int c = cg * 8 + j;
    float y = a.bt[c];
#pragma unroll
    for (int ii = 0; ii < ICH; ++ii) y = fmaf(a.Wt[c * ICH + ii], f[ii], y);
    size_t idx = ((size_t)(n * CC + c)) * TV + tv;
    a.out[idx] = sG[j] * fmaf(y, sSS[j], sSS[8 + j]) + a.x[idx];
  }
}

// ---------------------------------------------------------------------------
// Mega kernel: all three phases with hand-rolled grid barriers between them.
// __launch_bounds__(256, 4): VGPR hard-cap 128 -> 4 blocks/CU -> 1024 >= 800
// co-resident (the round-5 deadlock was the merged kernel exceeding 128 VGPR
// -> 2 blocks/CU -> 512 < 800 -> spin barrier never satisfied).
// ---------------------------------------------------------------------------
__global__ __launch_bounds__(256, 4) void mega_kernel(Args a) {
  __shared__ float smem_f[7936];             // 31,744 B union arena

  // Phase 1: proj + gate (1312 units over 800 blocks; u%8 preserved)
  for (int u = blockIdx.x; u < 1312; u += NBLK) proj_gate_unit(a, u);

  grid_barrier(a.bar + 0);

  // Phase 2: attention + BN partials (1:1)
  attn_unit(a, blockIdx.x, smem_f);

  grid_barrier(a.bar + 1);

  // Phase 3: finalize + apply (832 units over 800 blocks)
  for (int u = blockIdx.x; u < 832; u += NBLK) apply_unit(a, u, smem_f);
}

// ---------------------------------------------------------------------------
extern "C" void kernel_launch(void* const* d_in, const int* in_sizes, int n_in,
                              void* d_out, int out_size, void* d_ws, size_t ws_size,
                              hipStream_t stream) {
  char* ws = (char*)d_ws;

  // workspace layout (bytes) — total ~7.0 MB
  const size_t E = 819200;                    // N*TV*ICH elements
  Args a;
  a.x     = (const float*)d_in[0];
  a.Wv    = (const float*)d_in[1];
  a.bv    = (const float*)d_in[2];
  a.Wk    = (const float*)d_in[3];
  a.bk    = (const float*)d_in[4];
  a.Wq    = (const float*)d_in[5];
  a.bq    = (const float*)d_in[6];
  a.Wt    = (const float*)d_in[7];
  a.bt    = (const float*)d_in[8];
  a.gamma = (const float*)d_in[9];
  a.beta  = (const float*)d_in[10];
  a.W1    = (const float*)d_in[11];
  a.b1    = (const float*)d_in[12];
  a.W2    = (const float*)d_in[13];
  a.b2    = (const float*)d_in[14];
  a.Qb  = (__bf16*)(ws);                // 2E bytes
  a.Kb  = (__bf16*)(ws + 2*E);          // 2E bytes
  a.VTb = (__bf16*)(ws + 4*E);          // 2E bytes
  a.Pb  = (__bf16*)(ws + 6*E);          // 2E bytes
  a.GSP = (float*) (ws + 8*E);          // 409600 B column-major partials
  a.AVG = (float*) (ws + 8*E + 409600); // 4096 B (NB*CC)
  a.bar = (unsigned*)(ws + 8*E + 409600 + 4096); // 2 barrier counters
  a.out = (float*)d_out;

  // zero the barrier counters (workspace is poisoned each run; memset is a
  // capture-safe stream op and replays as a graph node before the kernel)
  (void)hipMemsetAsync((void*)a.bar, 0, 2 * sizeof(unsigned), stream);

  mega_kernel<<<NBLK, 256, 0, stream>>>(a);
}

// Round 8
// 149.672 us; speedup vs baseline: 4.2803x; 4.2803x over previous
//
#include <hip/hip_runtime.h>
#include <hip/hip_bf16.h>
#include <math.h>

// Problem constants
#define NB   16      // batch
#define CC   64      // channels
#define ICH  32      // inter channels
#define TV   1600    // T*V = 64*25
#define NTV  (NB*TV) // 25600
#define ABLK 1600    // attn grid: 16 n x 100 row-tiles of 16 rows

typedef __bf16 bf16x8 __attribute__((ext_vector_type(8)));
typedef __bf16 bf16x4 __attribute__((ext_vector_type(4)));
typedef float  f32x4  __attribute__((ext_vector_type(4)));

// ---------------------------------------------------------------------------
// K1: 1x1 conv projections, p-split (12-way: 3 proj x 4 o-groups), XCD-
// SWIZZLED so all 12 blocks sharing an x-tile land on ONE XCD residue class.
// Proj blocks 0..1247 (48 no-op), gate blocks 1248..1311.
//  Qb = k_x [N,TV,32] (PRE-SCALED by log2e -> attn uses v_exp_f32 directly)
//  Kb = q_x [N,TV,32]   VTb = v_x^T [N,32,TV]   AVG -> workspace
// ---------------------------------------------------------------------------
__global__ __launch_bounds__(256) void proj_gate_kernel(
    const float* __restrict__ x,
    const float* __restrict__ Wv, const float* __restrict__ bv,
    const float* __restrict__ Wk, const float* __restrict__ bk,
    const float* __restrict__ Wq, const float* __restrict__ bq,
    __bf16* __restrict__ Qb, __bf16* __restrict__ Kb,
    __bf16* __restrict__ VTb, float* __restrict__ AVG) {
  if (blockIdx.x >= 1248) {
    // ---- ChannelGate phase 1: per-(n, c) mean over TV ----
    int b = blockIdx.x - 1248;
    int n = b >> 2, cq = b & 3;
    int c16 = threadIdx.x >> 4, l = threadIdx.x & 15;
    int c = cq * 16 + c16;
    const float4* xp = (const float4*)(x + ((size_t)n * CC + c) * TV) + l;
    float s = 0.f;
#pragma unroll
    for (int i = 0; i < 25; ++i) {
      float4 v = xp[i * 16];
      s += v.x + v.y + v.z + v.w;
    }
#pragma unroll
    for (int off = 8; off >= 1; off >>= 1) s += __shfl_down(s, off, 16);
    if (l == 0) AVG[n * CC + c] = s * (1.0f / (float)TV);
    return;
  }

  // XCD swizzle: XCD = blockIdx % 8; tile = r + 8g so all subs of a tile
  // share residue r -> same XCD.
  int r = blockIdx.x & 7;
  int i = blockIdx.x >> 3;               // 0..155
  int g = i / 12, sub = i % 12;          // sub = p*4 + og
  int tile = r + 8 * g;
  if (tile >= 100) return;               // 48 no-op blocks

  int p = sub >> 2, og = sub & 3;
  int ob = og * 8;
  int tvIdx = tile * 256 + threadIdx.x;  // 0..25599
  int n = tvIdx / TV, tv = tvIdx % TV;

  const float* W; const float* B;
  if (p == 0)      { W = Wv; B = bv; }
  else if (p == 1) { W = Wk; B = bk; }
  else             { W = Wq; B = bq; }

  float acc[8];
#pragma unroll
  for (int j = 0; j < 8; ++j) acc[j] = B[ob + j];

  const float* xp = x + (size_t)n * CC * TV + tv;
#pragma unroll 16
  for (int c = 0; c < CC; ++c) {
    float xc = xp[c * TV];
#pragma unroll
    for (int j = 0; j < 8; ++j)
      acc[j] = fmaf(W[(ob + j) * CC + c], xc, acc[j]);
  }

  if (p == 0) {                           // v_x -> transposed
#pragma unroll
    for (int j = 0; j < 8; ++j)
      VTb[(n * ICH + ob + j) * TV + tv] = (__bf16)acc[j];
  } else {
    if (p == 1) {                         // fold log2(e): attn uses v_exp_f32
#pragma unroll
      for (int j = 0; j < 8; ++j)
        acc[j] *= 1.4426950408889634f;
    }
    bf16x8 t;
#pragma unroll
    for (int j = 0; j < 8; ++j) t[j] = (__bf16)acc[j];
    int base = (n * TV + tv) * ICH + ob;
    if (p == 1) *(bf16x8*)(Qb + base) = t;   // k_x -> attention rows
    else        *(bf16x8*)(Kb + base) = t;   // q_x -> attention cols
  }
}

// ---------------------------------------------------------------------------
// K2: MFMA flash attention, 16-ROW m-tiles (1 per block, was 2): grid 1600,
// LDS 16,640 B -> ~6 blocks/CU available (was grid-limited to 3.1 at 800).
// Swapped QK^T (mfma(K,Q) -> P^T) -> packed ds_write_b64; exp2 log2-domain;
// K+V register pipelining; fused BN-stats epilogue. BN partials COLUMN-MAJOR
// GSP[c*1600 + block]. XCD mapping: b&7 -> n-pair (K/V L2-resident per XCD).
// ---------------------------------------------------------------------------
__global__ __launch_bounds__(256) void attn_kernel(
    const __bf16* __restrict__ Qb, const __bf16* __restrict__ Kb,
    const __bf16* __restrict__ VTb, __bf16* __restrict__ P,
    const float* __restrict__ Wt, const float* __restrict__ bt,
    float* __restrict__ GSP) {
  __shared__ float smem_f[4160];             // 16,640 B union arena
  int b = blockIdx.x;
  int r8 = b & 7, qq = b >> 3;               // qq in [0,200)
  int n = r8 * 2 + (qq >= 100 ? 1 : 0);
  int rowTile = (qq >= 100) ? qq - 100 : qq;
  int row0 = rowTile * 16;

  int w = threadIdx.x >> 6;
  int lane = threadIdx.x & 63;
  int m = lane & 15, q = lane >> 4;

  // main-loop Pbuf: per wave 16 x 72 bf16 = 1152 elem (2304 B)
  __bf16* Pw = (__bf16*)smem_f + w * 1152;

  const __bf16* Qn = Qb  + (size_t)n * TV * ICH;
  const __bf16* Kn = Kb  + (size_t)n * TV * ICH;
  const __bf16* Vn = VTb + (size_t)n * ICH * TV;

  bf16x8 aQ0 = *(const bf16x8*)(Qn + (row0 + m) * ICH + q * 8);

  f32x4 o00 = {0.f,0.f,0.f,0.f}, o01 = {0.f,0.f,0.f,0.f};
  float ls0 = 0.f;                           // lane-local rowsum (row = m)
  const f32x4 zero = {0.f,0.f,0.f,0.f};

  // chunk offset for this wave, rotated per block so the extra (7th) chunk
  // (offset 0) moves between waves across blocks.
  int ow = (w + b) & 3;                      // offset residue; 0 -> 7 chunks
  int nch = (ow == 0) ? 7 : 6;

  // preload chunk 0's K fragments into registers
  bf16x8 bKc[4];
  {
    int s0 = ow * 64;
#pragma unroll
    for (int st = 0; st < 4; ++st)
      bKc[st] = *(const bf16x8*)(Kn + (s0 + st * 16 + m) * ICH + q * 8);
  }

  for (int j = 0; j < nch; ++j) {
    int s0 = (4 * j + ow) * 64;
    // ---- swapped QK^T: C = P^T tile, lane (q,m): col=m (attn row),
    //      rows = s-offset st*16 + q*4 + r (4 consecutive s per lane) ----
#pragma unroll
    for (int st = 0; st < 4; ++st) {
      f32x4 a0 = __builtin_amdgcn_mfma_f32_16x16x32_bf16(bKc[st], aQ0, zero, 0, 0, 0);
      bf16x4 t0;
#pragma unroll
      for (int r = 0; r < 4; ++r) {
        float e0 = __builtin_amdgcn_exp2f(a0[r]); ls0 += e0; t0[r] = (__bf16)e0;
      }
      int off = m * 72 + st * 16 + q * 4;    // byte off m*144+st*32+q*8: 8B-aligned
      *(bf16x4*)(Pw + off) = t0;             // one ds_write_b64 per st
    }
    // prefetch next chunk's K + this chunk's V BEFORE the wait
    int chn = 4 * (j + 1) + ow;
    int s0n = (chn < 25 ? chn : 0) * 64;       // clamped, wave-uniform
    bf16x8 bKn[4], pV[2][2];
#pragma unroll
    for (int st = 0; st < 4; ++st)
      bKn[st] = *(const bf16x8*)(Kn + (s0n + st * 16 + m) * ICH + q * 8);
#pragma unroll
    for (int kc = 0; kc < 2; ++kc)
#pragma unroll
      for (int ict = 0; ict < 2; ++ict)
        pV[kc][ict] = *(const bf16x8*)(Vn + (ict * 16 + m) * TV + s0 + kc * 32 + q * 8);
    // in-wave DS write->read ordering
    asm volatile("s_waitcnt lgkmcnt(0)" ::: "memory");
    // ---- P*V: 2 k-chunks of 32 s ----
#pragma unroll
    for (int kc = 0; kc < 2; ++kc) {
      bf16x8 aP0 = *(const bf16x8*)(Pw + m * 72 + kc * 32 + q * 8);
      o00 = __builtin_amdgcn_mfma_f32_16x16x32_bf16(aP0, pV[kc][0], o00, 0, 0, 0);
      o01 = __builtin_amdgcn_mfma_f32_16x16x32_bf16(aP0, pV[kc][1], o01, 0, 0, 0);
    }
#pragma unroll
    for (int st = 0; st < 4; ++st) bKc[st] = bKn[st];
  }

  // row sums: lane (q,m) has the partial for row m over its q-subset of s;
  // sum the 4 q-lanes, then gather into the merge layout (row = q*4+r).
  ls0 += __shfl_xor(ls0, 16, 64); ls0 += __shfl_xor(ls0, 32, 64);
  f32x4 lv0;
#pragma unroll
  for (int r = 0; r < 4; ++r) {
    int src = q * 4 + r;                    // lane src (q=0 group) holds row src
    lv0[r] = __shfl(ls0, src, 64);
  }

  // ---- epilogue arena (aliases Pbuf, which is dead after the barrier) ----
  float* pub = smem_f;                       // [4 waves][64 lanes][12]
  float* Pl  = smem_f + 3072;                // [16][36] normalized P tile
  float* red = smem_f + 3648;                // [4 waves][128]

  __syncthreads();
  f32x4* mp = (f32x4*)(pub + (w * 64 + lane) * 12);
  mp[0] = o00; mp[1] = o01; mp[2] = lv0;
  __syncthreads();

  // parallel merge: wave w (w<2) owns o-group w (cols w*16..w*16+15).
  if (w < 2) {
    const f32x4* p0 = (const f32x4*)(pub + lane * 12);
    f32x4 osum = p0[w];
    f32x4 lsum = p0[2];
#pragma unroll
    for (int ww = 1; ww < 4; ++ww) {
      const f32x4* pp = (const f32x4*)(pub + (ww * 64 + lane) * 12);
      f32x4 ov = pp[w], lv = pp[2];
#pragma unroll
      for (int r = 0; r < 4; ++r) { osum[r] += ov[r]; lsum[r] += lv[r]; }
    }
    int colh = w * 16;
#pragma unroll
    for (int r = 0; r < 4; ++r) {
      float p = osum[r] / lsum[r];
      int row = q * 4 + r;
      P[(n * TV + row0 + row) * ICH + colh + m] = (__bf16)p;
      Pl[row * 36 + colh + m] = p;
    }
  }
  __syncthreads();

  // ---- fused BN stats: thread (c = t&63, rows w*4..w*4+3) 64ch dot.
  // Pl reads are wave-uniform b128 broadcasts (stride 36 -> 16B-aligned).
  int c = threadIdx.x & 63;
  float wr[ICH];
#pragma unroll
  for (int i = 0; i < ICH; ++i) wr[i] = Wt[c * ICH + i];
  float bc = bt[c];
  float sy = 0.f, sy2 = 0.f;
#pragma unroll
  for (int rr = 0; rr < 4; ++rr) {
    const f32x4* pr = (const f32x4*)(Pl + (w * 4 + rr) * 36);
    float y = bc;
#pragma unroll
    for (int u = 0; u < 8; ++u) {
      f32x4 pv = pr[u];
#pragma unroll
      for (int k = 0; k < 4; ++k) y = fmaf(wr[u * 4 + k], pv[k], y);
    }
    sy += y; sy2 += y * y;
  }
  red[w * 128 + c]      = sy;
  red[w * 128 + 64 + c] = sy2;
  __syncthreads();
  if (threadIdx.x < 128) {
    int t = threadIdx.x;
    float s = red[t] + red[128 + t] + red[256 + t] + red[384 + t];
    GSP[(size_t)t * ABLK + blockIdx.x] = s;  // COLUMN-MAJOR: consumer-contiguous
  }
}

// ---------------------------------------------------------------------------
// K3: fused finalize + apply. Each block redundantly recomputes the 16
// BN-stat column sums it needs (its 8 channels' sum-y / sum-y2 over the 1600
// GSP slots; column-major -> coalesced 64 B runs) plus the ChannelGate MLP,
// then recomputes y from bf16 P and applies BN + gate + residual.
// XCD-SWIZZLED over P tv-tiles. Grid 832 (32 no-op).
// ---------------------------------------------------------------------------
__global__ __launch_bounds__(256) void apply_kernel(
    const __bf16* __restrict__ P, const float* __restrict__ Wt,
    const float* __restrict__ bt, const float* __restrict__ GSP,
    const float* __restrict__ gamma, const float* __restrict__ beta,
    const float* __restrict__ AVG,
    const float* __restrict__ W1, const float* __restrict__ b1,
    const float* __restrict__ W2, const float* __restrict__ b2,
    const float* __restrict__ x, float* __restrict__ out) {
  int r = blockIdx.x & 7;
  int i = blockIdx.x >> 3;              // 0..103
  int cg = i & 7, h = i >> 3;           // h in 0..12
  int tb = r + 8 * h;
  if (tb >= 100) return;                // 32 no-op blocks

  int tvIdx = tb * 256 + threadIdx.x;
  int n = tvIdx / TV, tv = tvIdx % TV;

  __shared__ float sstat[16];           // [0..7]=sum y, [8..15]=sum y^2
  __shared__ float sSS[16];             // [0..7]=scale, [8..15]=shift
  __shared__ float sG[8];               // gate for (n, cg*8..cg*8+7)

  // ---- Phase A: 16 threads/column sum 100 slots each (contiguous stride-16
  // runs within a column-major GSP row of 1600) ----
  {
    int colid = threadIdx.x >> 4;       // 0..15
    int sub = threadIdx.x & 15;         // 0..15
    int c8 = colid & 7;
    int gc = (colid < 8) ? (cg * 8 + c8) : (64 + cg * 8 + c8);
    const float* gp = GSP + (size_t)gc * ABLK;
    float s = 0.f;
#pragma unroll
    for (int k = 0; k < 100; ++k) s += gp[sub + k * 16];
#pragma unroll
    for (int off = 8; off >= 1; off >>= 1) s += __shfl_down(s, off, 16);
    if (sub == 0) sstat[colid] = s;
  }
  __syncthreads();
  if (threadIdx.x < 8) {
    int c8 = threadIdx.x;
    int c = cg * 8 + c8;
    float mean = sstat[c8] * (1.f / (float)NTV);
    float var  = sstat[8 + c8] * (1.f / (float)NTV) - mean * mean;
    float scale = rsqrtf(var + 1e-5f) * gamma[c];
    sSS[c8] = scale;
    sSS[8 + c8] = beta[c] - mean * scale;
    // ChannelGate MLP for this n (redundant across the 8 lanes, tiny)
    float hh[4];
#pragma unroll
    for (int jj = 0; jj < 4; ++jj) {
      float hv = b1[jj];
      for (int c2 = 0; c2 < CC; ++c2)
        hv = fmaf(W1[jj * CC + c2], AVG[n * CC + c2], hv);
      hh[jj] = fmaxf(hv, 0.f);
    }
    float g = b2[c];
#pragma unroll
    for (int jj = 0; jj < 4; ++jj) g = fmaf(W2[c * 4 + jj], hh[jj], g);
    sG[c8] = 1.f / (1.f + __expf(-g));
  }
  __syncthreads();

  // ---- Phase B: recompute y for 8 channels from bf16 P, apply ----
  float f[ICH];
  const bf16x8* pp = (const bf16x8*)(P + ((size_t)(n * TV + tv)) * ICH);
#pragma unroll
  for (int u = 0; u < 4; ++u) {
    bf16x8 v = pp[u];
#pragma unroll
    for (int j = 0; j < 8; ++j) f[u * 8 + j] = (float)v[j];
  }

#pragma unroll
  for (int j = 0; j < 8; ++j) {
    int c = cg * 8 + j;
    float y = bt[c];
#pragma unroll
    for (int ii = 0; ii < ICH; ++ii) y = fmaf(Wt[c * ICH + ii], f[ii], y);
    size_t idx = ((size_t)(n * CC + c)) * TV + tv;
    out[idx] = sG[j] * fmaf(y, sSS[j], sSS[8 + j]) + x[idx];
  }
}

// ---------------------------------------------------------------------------
extern "C" void kernel_launch(void* const* d_in, const int* in_sizes, int n_in,
                              void* d_out, int out_size, void* d_ws, size_t ws_size,
                              hipStream_t stream) {
  const float* x     = (const float*)d_in[0];
  const float* Wv    = (const float*)d_in[1];
  const float* bv    = (const float*)d_in[2];
  const float* Wk    = (const float*)d_in[3];
  const float* bk    = (const float*)d_in[4];
  const float* Wq    = (const float*)d_in[5];
  const float* bq    = (const float*)d_in[6];
  const float* Wt    = (const float*)d_in[7];
  const float* bt    = (const float*)d_in[8];
  const float* gamma = (const float*)d_in[9];
  const float* beta  = (const float*)d_in[10];
  const float* W1    = (const float*)d_in[11];
  const float* b1    = (const float*)d_in[12];
  const float* W2    = (const float*)d_in[13];
  const float* b2    = (const float*)d_in[14];
  float* out = (float*)d_out;
  char* ws = (char*)d_ws;

  // workspace layout (bytes) — total ~7.4 MB
  const size_t E = 819200;                    // N*TV*ICH elements
  __bf16* Qb  = (__bf16*)(ws);                // 2E bytes
  __bf16* Kb  = (__bf16*)(ws + 2*E);          // 2E bytes
  __bf16* VTb = (__bf16*)(ws + 4*E);          // 2E bytes
  __bf16* Pb  = (__bf16*)(ws + 6*E);          // 2E bytes
  float*  GSP = (float*) (ws + 8*E);          // 128*1600*4 = 819200 B
  float*  AVG = (float*) (ws + 8*E + 819200); // 4096 B (NB*CC)

  proj_gate_kernel<<<1312, 256, 0, stream>>>(x, Wv, bv, Wk, bk, Wq, bq,
                                             Qb, Kb, VTb, AVG);
  attn_kernel<<<ABLK, 256, 0, stream>>>(Qb, Kb, VTb, Pb, Wt, bt, GSP);
  apply_kernel<<<832, 256, 0, stream>>>(Pb, Wt, bt, GSP, gamma, beta, AVG,
                                        W1, b1, W2, b2, x, out);
}

// Round 9
// 139.133 us; speedup vs baseline: 4.6045x; 1.0757x over previous
//
#include <hip/hip_runtime.h>
#include <hip/hip_bf16.h>
#include <math.h>

// Problem constants
#define NB   16      // batch
#define CC   64      // channels
#define ICH  32      // inter channels
#define TV   1600    // T*V = 64*25
#define NTV  (NB*TV) // 25600

typedef __bf16 bf16x8 __attribute__((ext_vector_type(8)));
typedef __bf16 bf16x4 __attribute__((ext_vector_type(4)));
typedef float  f32x4  __attribute__((ext_vector_type(4)));

// ---------------------------------------------------------------------------
// K1: 1x1 conv projections, p-split (12-way: 3 proj x 4 o-groups), XCD-
// SWIZZLED so all 12 blocks sharing an x-tile land on ONE XCD residue class.
// Proj blocks 0..1247 (48 no-op), gate blocks 1248..1311.
//  Qb = k_x [N,TV,32] (PRE-SCALED by log2e -> attn uses v_exp_f32 directly)
//  Kb = q_x [N,TV,32]   VTb = v_x^T [N,32,TV]   AVG -> workspace
// ---------------------------------------------------------------------------
__global__ __launch_bounds__(256) void proj_gate_kernel(
    const float* __restrict__ x,
    const float* __restrict__ Wv, const float* __restrict__ bv,
    const float* __restrict__ Wk, const float* __restrict__ bk,
    const float* __restrict__ Wq, const float* __restrict__ bq,
    __bf16* __restrict__ Qb, __bf16* __restrict__ Kb,
    __bf16* __restrict__ VTb, float* __restrict__ AVG) {
  if (blockIdx.x >= 1248) {
    // ---- ChannelGate phase 1: per-(n, c) mean over TV ----
    int b = blockIdx.x - 1248;
    int n = b >> 2, cq = b & 3;
    int c16 = threadIdx.x >> 4, l = threadIdx.x & 15;
    int c = cq * 16 + c16;
    const float4* xp = (const float4*)(x + ((size_t)n * CC + c) * TV) + l;
    float s = 0.f;
#pragma unroll
    for (int i = 0; i < 25; ++i) {
      float4 v = xp[i * 16];
      s += v.x + v.y + v.z + v.w;
    }
#pragma unroll
    for (int off = 8; off >= 1; off >>= 1) s += __shfl_down(s, off, 16);
    if (l == 0) AVG[n * CC + c] = s * (1.0f / (float)TV);
    return;
  }

  // XCD swizzle: XCD = blockIdx % 8; tile = r + 8g so all subs of a tile
  // share residue r -> same XCD.
  int r = blockIdx.x & 7;
  int i = blockIdx.x >> 3;               // 0..155
  int g = i / 12, sub = i % 12;          // sub = p*4 + og
  int tile = r + 8 * g;
  if (tile >= 100) return;               // 48 no-op blocks

  int p = sub >> 2, og = sub & 3;
  int ob = og * 8;
  int tvIdx = tile * 256 + threadIdx.x;  // 0..25599
  int n = tvIdx / TV, tv = tvIdx % TV;

  const float* W; const float* B;
  if (p == 0)      { W = Wv; B = bv; }
  else if (p == 1) { W = Wk; B = bk; }
  else             { W = Wq; B = bq; }

  float acc[8];
#pragma unroll
  for (int j = 0; j < 8; ++j) acc[j] = B[ob + j];

  const float* xp = x + (size_t)n * CC * TV + tv;
#pragma unroll 16
  for (int c = 0; c < CC; ++c) {
    float xc = xp[c * TV];
#pragma unroll
    for (int j = 0; j < 8; ++j)
      acc[j] = fmaf(W[(ob + j) * CC + c], xc, acc[j]);
  }

  if (p == 0) {                           // v_x -> transposed
#pragma unroll
    for (int j = 0; j < 8; ++j)
      VTb[(n * ICH + ob + j) * TV + tv] = (__bf16)acc[j];
  } else {
    if (p == 1) {                         // fold log2(e): attn uses v_exp_f32
#pragma unroll
      for (int j = 0; j < 8; ++j)
        acc[j] *= 1.4426950408889634f;
    }
    bf16x8 t;
#pragma unroll
    for (int j = 0; j < 8; ++j) t[j] = (__bf16)acc[j];
    int base = (n * TV + tv) * ICH + ob;
    if (p == 1) *(bf16x8*)(Qb + base) = t;   // k_x -> attention rows
    else        *(bf16x8*)(Kb + base) = t;   // q_x -> attention cols
  }
}

// ---------------------------------------------------------------------------
// K2: MFMA flash attention (round-2 structure: 800 blocks, 2 m-tiles/wave,
// shared bK feeds both tiles) + K AND V register double-buffering (V was
// loaded and used within one chunk -> ~250cy exposed L2 latency per chunk;
// now pVc/pVn ping-pong like K). Swapped QK^T -> packed ds_write_b64; exp2
// log2-domain. Epilogue: BN-stats loop STORES its f32 y values to Yb
// [c][n*TV+tv] (global P store dropped -- apply no longer recomputes the
// conv). BN partials COLUMN-MAJOR GSP[c*800+b]. LDS 31,744 B.
// ---------------------------------------------------------------------------
__global__ __launch_bounds__(256) void attn_kernel(
    const __bf16* __restrict__ Qb, const __bf16* __restrict__ Kb,
    const __bf16* __restrict__ VTb, float* __restrict__ Yb,
    const float* __restrict__ Wt, const float* __restrict__ bt,
    float* __restrict__ GSP) {
  __shared__ float smem_f[7936];             // 31,744 B union arena
  int b = blockIdx.x;
  int r8 = b & 7, qq = b >> 3;               // qq in [0,100)
  int n = r8 * 2 + (qq >= 50 ? 1 : 0);
  int rowTile = (qq >= 50) ? qq - 50 : qq;
  int row0 = rowTile * 32;

  int w = threadIdx.x >> 6;
  int lane = threadIdx.x & 63;
  int m = lane & 15, q = lane >> 4;

  // main-loop Pbuf: per wave 2 tiles x 16 x 72 bf16 = 2304 elem (4608 B)
  __bf16* Pw = (__bf16*)smem_f + w * 2304;

  const __bf16* Qn = Qb  + (size_t)n * TV * ICH;
  const __bf16* Kn = Kb  + (size_t)n * TV * ICH;
  const __bf16* Vn = VTb + (size_t)n * ICH * TV;

  bf16x8 aQ0 = *(const bf16x8*)(Qn + (row0 + m) * ICH + q * 8);
  bf16x8 aQ1 = *(const bf16x8*)(Qn + (row0 + 16 + m) * ICH + q * 8);

  f32x4 o00 = {0.f,0.f,0.f,0.f}, o01 = {0.f,0.f,0.f,0.f};
  f32x4 o10 = {0.f,0.f,0.f,0.f}, o11 = {0.f,0.f,0.f,0.f};
  float ls0 = 0.f, ls1 = 0.f;                // lane-local rowsum (row = m)
  const f32x4 zero = {0.f,0.f,0.f,0.f};

  // chunk offset for this wave, rotated per block so the extra (7th) chunk
  // (offset 0) moves between waves across blocks.
  int ow = (w + b) & 3;                      // offset residue; 0 -> 7 chunks
  int nch = (ow == 0) ? 7 : 6;

  // preload chunk 0's K fragments AND V fragments into registers
  bf16x8 bKc[4], pVc[2][2];
  {
    int s0 = ow * 64;
#pragma unroll
    for (int st = 0; st < 4; ++st)
      bKc[st] = *(const bf16x8*)(Kn + (s0 + st * 16 + m) * ICH + q * 8);
#pragma unroll
    for (int kc = 0; kc < 2; ++kc)
#pragma unroll
      for (int ict = 0; ict < 2; ++ict)
        pVc[kc][ict] = *(const bf16x8*)(Vn + (ict * 16 + m) * TV + s0 + kc * 32 + q * 8);
  }

  for (int j = 0; j < nch; ++j) {
    int s0 = (4 * j + ow) * 64;
    (void)s0;
    // ---- swapped QK^T: C = P^T tile, lane (q,m): col=m (attn row),
    //      rows = s-offset st*16 + q*4 + r (4 consecutive s per lane) ----
#pragma unroll
    for (int st = 0; st < 4; ++st) {
      f32x4 a0 = __builtin_amdgcn_mfma_f32_16x16x32_bf16(bKc[st], aQ0, zero, 0, 0, 0);
      f32x4 a1 = __builtin_amdgcn_mfma_f32_16x16x32_bf16(bKc[st], aQ1, zero, 0, 0, 0);
      bf16x4 t0, t1;
#pragma unroll
      for (int r = 0; r < 4; ++r) {
        float e0 = __builtin_amdgcn_exp2f(a0[r]); ls0 += e0; t0[r] = (__bf16)e0;
        float e1 = __builtin_amdgcn_exp2f(a1[r]); ls1 += e1; t1[r] = (__bf16)e1;
      }
      int off = m * 72 + st * 16 + q * 4;    // byte off m*144+st*32+q*8: 8B-aligned
      *(bf16x4*)(Pw + off)        = t0;      // one ds_write_b64 per st/tile
      *(bf16x4*)(Pw + 1152 + off) = t1;
    }
    // prefetch NEXT chunk's K and V before the wait (both double-buffered)
    int chn = 4 * (j + 1) + ow;
    int s0n = (chn < 25 ? chn : 0) * 64;       // clamped, wave-uniform
    bf16x8 bKn[4], pVn[2][2];
#pragma unroll
    for (int st = 0; st < 4; ++st)
      bKn[st] = *(const bf16x8*)(Kn + (s0n + st * 16 + m) * ICH + q * 8);
#pragma unroll
    for (int kc = 0; kc < 2; ++kc)
#pragma unroll
      for (int ict = 0; ict < 2; ++ict)
        pVn[kc][ict] = *(const bf16x8*)(Vn + (ict * 16 + m) * TV + s0n + kc * 32 + q * 8);
    // in-wave DS write->read ordering
    asm volatile("s_waitcnt lgkmcnt(0)" ::: "memory");
    // ---- P*V: 2 k-chunks of 32 s (V from registers, loaded last chunk) ----
#pragma unroll
    for (int kc = 0; kc < 2; ++kc) {
      bf16x8 aP0 = *(const bf16x8*)(Pw + m * 72 + kc * 32 + q * 8);
      bf16x8 aP1 = *(const bf16x8*)(Pw + 1152 + m * 72 + kc * 32 + q * 8);
      o00 = __builtin_amdgcn_mfma_f32_16x16x32_bf16(aP0, pVc[kc][0], o00, 0, 0, 0);
      o10 = __builtin_amdgcn_mfma_f32_16x16x32_bf16(aP1, pVc[kc][0], o10, 0, 0, 0);
      o01 = __builtin_amdgcn_mfma_f32_16x16x32_bf16(aP0, pVc[kc][1], o01, 0, 0, 0);
      o11 = __builtin_amdgcn_mfma_f32_16x16x32_bf16(aP1, pVc[kc][1], o11, 0, 0, 0);
    }
#pragma unroll
    for (int st = 0; st < 4; ++st) bKc[st] = bKn[st];
#pragma unroll
    for (int kc = 0; kc < 2; ++kc)
#pragma unroll
      for (int ict = 0; ict < 2; ++ict) pVc[kc][ict] = pVn[kc][ict];
  }

  // row sums: lane (q,m) has the partial for row m over its q-subset of s;
  // sum the 4 q-lanes, then gather into the merge layout (row = q*4+r).
  ls0 += __shfl_xor(ls0, 16, 64); ls0 += __shfl_xor(ls0, 32, 64);
  ls1 += __shfl_xor(ls1, 16, 64); ls1 += __shfl_xor(ls1, 32, 64);
  f32x4 lv0, lv1;
#pragma unroll
  for (int r = 0; r < 4; ++r) {
    int src = q * 4 + r;                    // lane src (q=0 group) holds row src
    lv0[r] = __shfl(ls0, src, 64);
    lv1[r] = __shfl(ls1, src, 64);
  }

  // ---- epilogue arena (aliases Pbuf, which is dead after the barrier) ----
  float* pub = smem_f;                       // [4 waves][64 lanes][24]
  float* Pl  = smem_f + 6144;                // [32][36] normalized P tile
  float* red = smem_f + 7296;                // [4 waves][128]

  __syncthreads();
  f32x4* mp = (f32x4*)(pub + (w * 64 + lane) * 24);
  mp[0] = o00; mp[1] = o01; mp[2] = o10; mp[3] = o11;
  mp[4] = lv0; mp[5] = lv1;
  __syncthreads();

  // parallel merge: wave w owns group w; ls0 for w<2, ls1 for w>=2.
  // P is NOT stored globally anymore -- only the f32 tile in LDS for BN/y.
  {
    int lsIdx = 4 + (w >> 1);
    const f32x4* p0 = (const f32x4*)(pub + lane * 24);
    f32x4 osum = p0[w];
    f32x4 lsum = p0[lsIdx];
#pragma unroll
    for (int ww = 1; ww < 4; ++ww) {
      const f32x4* pp = (const f32x4*)(pub + (ww * 64 + lane) * 24);
      f32x4 ov = pp[w], lv = pp[lsIdx];
#pragma unroll
      for (int r = 0; r < 4; ++r) { osum[r] += ov[r]; lsum[r] += lv[r]; }
    }
    int tile = w >> 1, colh = (w & 1) * 16;
#pragma unroll
    for (int r = 0; r < 4; ++r) {
      float p = osum[r] / lsum[r];
      int row = tile * 16 + q * 4 + r;
      Pl[row * 36 + colh + m] = p;
    }
  }
  __syncthreads();

  // ---- fused BN stats + y STORE: thread (c = t&63, rows w*8..w*8+7).
  // y is the final Trans_s conv output (f32, pre-normalization); stored to
  // Yb[c][n*TV + row] so apply is a pure streaming pass. Pl reads are
  // wave-uniform b128 broadcasts (stride 36 -> 16B-aligned).
  int c = threadIdx.x & 63;
  float wr[ICH];
#pragma unroll
  for (int i = 0; i < ICH; ++i) wr[i] = Wt[c * ICH + i];
  float bc = bt[c];
  float sy = 0.f, sy2 = 0.f;
  float* yout = Yb + (size_t)c * NTV + n * TV + row0 + w * 8;
#pragma unroll
  for (int rr = 0; rr < 8; ++rr) {
    const f32x4* pr = (const f32x4*)(Pl + (w * 8 + rr) * 36);
    float y = bc;
#pragma unroll
    for (int u = 0; u < 8; ++u) {
      f32x4 pv = pr[u];
#pragma unroll
      for (int k = 0; k < 4; ++k) y = fmaf(wr[u * 4 + k], pv[k], y);
    }
    yout[rr] = y;
    sy += y; sy2 += y * y;
  }
  red[w * 128 + c]      = sy;
  red[w * 128 + 64 + c] = sy2;
  __syncthreads();
  if (threadIdx.x < 128) {
    int t = threadIdx.x;
    float s = red[t] + red[128 + t] + red[256 + t] + red[384 + t];
    GSP[(size_t)t * 800 + b] = s;            // COLUMN-MAJOR: consumer-contiguous
  }
}

// ---------------------------------------------------------------------------
// K3: finalize + apply, now PURE STREAMING. Each block recomputes the 16
// BN-stat column sums for its 8 channels (column-major GSP -> coalesced
// 64 B runs) + ChannelGate MLP, then reads the f32 y values produced by the
// attn epilogue (no conv recompute, no P read) and applies BN + gate +
// residual. XCD-SWIZZLED over tv-tiles. Grid 832 (32 no-op).
// ---------------------------------------------------------------------------
__global__ __launch_bounds__(256) void apply_kernel(
    const float* __restrict__ Yb, const float* __restrict__ GSP,
    const float* __restrict__ gamma, const float* __restrict__ beta,
    const float* __restrict__ AVG,
    const float* __restrict__ W1, const float* __restrict__ b1,
    const float* __restrict__ W2, const float* __restrict__ b2,
    const float* __restrict__ x, float* __restrict__ out) {
  int r = blockIdx.x & 7;
  int i = blockIdx.x >> 3;              // 0..103
  int cg = i & 7, h = i >> 3;           // h in 0..12
  int tb = r + 8 * h;
  if (tb >= 100) return;                // 32 no-op blocks

  int tvIdx = tb * 256 + threadIdx.x;
  int n = tvIdx / TV, tv = tvIdx % TV;

  __shared__ float sstat[16];           // [0..7]=sum y, [8..15]=sum y^2
  __shared__ float sSS[16];             // [0..7]=scale, [8..15]=shift
  __shared__ float sG[8];               // gate for (n, cg*8..cg*8+7)

  // ---- Phase A: 16 threads/column sum 50 slots each (contiguous stride-16
  // runs within a column-major GSP row of 800) ----
  {
    int colid = threadIdx.x >> 4;       // 0..15
    int sub = threadIdx.x & 15;         // 0..15
    int c8 = colid & 7;
    int gc = (colid < 8) ? (cg * 8 + c8) : (64 + cg * 8 + c8);
    const float* gp = GSP + (size_t)gc * 800;
    float s = 0.f;
#pragma unroll
    for (int k = 0; k < 50; ++k) s += gp[sub + k * 16];
#pragma unroll
    for (int off = 8; off >= 1; off >>= 1) s += __shfl_down(s, off, 16);
    if (sub == 0) sstat[colid] = s;
  }
  __syncthreads();
  if (threadIdx.x < 8) {
    int c8 = threadIdx.x;
    int c = cg * 8 + c8;
    float mean = sstat[c8] * (1.f / (float)NTV);
    float var  = sstat[8 + c8] * (1.f / (float)NTV) - mean * mean;
    float scale = rsqrtf(var + 1e-5f) * gamma[c];
    sSS[c8] = scale;
    sSS[8 + c8] = beta[c] - mean * scale;
    // ChannelGate MLP for this n (redundant across the 8 lanes, tiny)
    float hh[4];
#pragma unroll
    for (int jj = 0; jj < 4; ++jj) {
      float hv = b1[jj];
      for (int c2 = 0; c2 < CC; ++c2)
        hv = fmaf(W1[jj * CC + c2], AVG[n * CC + c2], hv);
      hh[jj] = fmaxf(hv, 0.f);
    }
    float g = b2[c];
#pragma unroll
    for (int jj = 0; jj < 4; ++jj) g = fmaf(W2[c * 4 + jj], hh[jj], g);
    sG[c8] = 1.f / (1.f + __expf(-g));
  }
  __syncthreads();

  // ---- Phase B: stream y, apply BN + gate + residual ----
#pragma unroll
  for (int j = 0; j < 8; ++j) {
    int c = cg * 8 + j;
    float y = Yb[(size_t)c * NTV + n * TV + tv];
    size_t idx = ((size_t)(n * CC + c)) * TV + tv;
    out[idx] = sG[j] * fmaf(y, sSS[j], sSS[8 + j]) + x[idx];
  }
}

// ---------------------------------------------------------------------------
extern "C" void kernel_launch(void* const* d_in, const int* in_sizes, int n_in,
                              void* d_out, int out_size, void* d_ws, size_t ws_size,
                              hipStream_t stream) {
  const float* x     = (const float*)d_in[0];
  const float* Wv    = (const float*)d_in[1];
  const float* bv    = (const float*)d_in[2];
  const float* Wk    = (const float*)d_in[3];
  const float* bk    = (const float*)d_in[4];
  const float* Wq    = (const float*)d_in[5];
  const float* bq    = (const float*)d_in[6];
  const float* Wt    = (const float*)d_in[7];
  const float* bt    = (const float*)d_in[8];
  const float* gamma = (const float*)d_in[9];
  const float* beta  = (const float*)d_in[10];
  const float* W1    = (const float*)d_in[11];
  const float* b1    = (const float*)d_in[12];
  const float* W2    = (const float*)d_in[13];
  const float* b2    = (const float*)d_in[14];
  float* out = (float*)d_out;
  char* ws = (char*)d_ws;

  // workspace layout (bytes) — total ~11.9 MB
  const size_t E = 819200;                    // N*TV*ICH elements
  __bf16* Qb  = (__bf16*)(ws);                // 2E bytes
  __bf16* Kb  = (__bf16*)(ws + 2*E);          // 2E bytes
  __bf16* VTb = (__bf16*)(ws + 4*E);          // 2E bytes
  float*  Yb  = (float*) (ws + 6*E);          // CC*NTV*4 = 6,553,600 B
  float*  GSP = (float*) (ws + 6*E + 6553600);          // 128*800*4 = 409600 B
  float*  AVG = (float*) (ws + 6*E + 6553600 + 409600); // 4096 B (NB*CC)

  proj_gate_kernel<<<1312, 256, 0, stream>>>(x, Wv, bv, Wk, bk, Wq, bq,
                                             Qb, Kb, VTb, AVG);
  attn_kernel<<<NB * 50, 256, 0, stream>>>(Qb, Kb, VTb, Yb, Wt, bt, GSP);
  apply_kernel<<<832, 256, 0, stream>>>(Yb, GSP, gamma, beta, AVG,
                                        W1, b1, W2, b2, x, out);
}

// Round 10
// 138.721 us; speedup vs baseline: 4.6182x; 1.0030x over previous
//
#include <hip/hip_runtime.h>
#include <hip/hip_bf16.h>
#include <math.h>

// Problem constants
#define NB   16      // batch
#define CC   64      // channels
#define ICH  32      // inter channels
#define TV   1600    // T*V = 64*25
#define NTV  (NB*TV) // 25600

typedef __bf16 bf16x8 __attribute__((ext_vector_type(8)));
typedef __bf16 bf16x4 __attribute__((ext_vector_type(4)));
typedef float  f32x4  __attribute__((ext_vector_type(4)));

// ---------------------------------------------------------------------------
// K1: 1x1 conv projections, p-split (12-way: 3 proj x 4 o-groups), XCD-
// SWIZZLED so all 12 blocks sharing an x-tile land on ONE XCD residue class.
// Proj blocks 0..1247 (48 no-op), gate blocks 1248..1311.
//  Qb = k_x [N,TV,32] (PRE-SCALED by log2e -> attn uses v_exp_f32 directly)
//  Kb = q_x [N,TV,32]   VTb = v_x^T [N,32,TV]   AVG -> workspace
// ---------------------------------------------------------------------------
__global__ __launch_bounds__(256) void proj_gate_kernel(
    const float* __restrict__ x,
    const float* __restrict__ Wv, const float* __restrict__ bv,
    const float* __restrict__ Wk, const float* __restrict__ bk,
    const float* __restrict__ Wq, const float* __restrict__ bq,
    __bf16* __restrict__ Qb, __bf16* __restrict__ Kb,
    __bf16* __restrict__ VTb, float* __restrict__ AVG) {
  if (blockIdx.x >= 1248) {
    // ---- ChannelGate phase 1: per-(n, c) mean over TV ----
    int b = blockIdx.x - 1248;
    int n = b >> 2, cq = b & 3;
    int c16 = threadIdx.x >> 4, l = threadIdx.x & 15;
    int c = cq * 16 + c16;
    const float4* xp = (const float4*)(x + ((size_t)n * CC + c) * TV) + l;
    float s = 0.f;
#pragma unroll
    for (int i = 0; i < 25; ++i) {
      float4 v = xp[i * 16];
      s += v.x + v.y + v.z + v.w;
    }
#pragma unroll
    for (int off = 8; off >= 1; off >>= 1) s += __shfl_down(s, off, 16);
    if (l == 0) AVG[n * CC + c] = s * (1.0f / (float)TV);
    return;
  }

  // XCD swizzle: XCD = blockIdx % 8; tile = r + 8g so all subs of a tile
  // share residue r -> same XCD.
  int r = blockIdx.x & 7;
  int i = blockIdx.x >> 3;               // 0..155
  int g = i / 12, sub = i % 12;          // sub = p*4 + og
  int tile = r + 8 * g;
  if (tile >= 100) return;               // 48 no-op blocks

  int p = sub >> 2, og = sub & 3;
  int ob = og * 8;
  int tvIdx = tile * 256 + threadIdx.x;  // 0..25599
  int n = tvIdx / TV, tv = tvIdx % TV;

  const float* W; const float* B;
  if (p == 0)      { W = Wv; B = bv; }
  else if (p == 1) { W = Wk; B = bk; }
  else             { W = Wq; B = bq; }

  float acc[8];
#pragma unroll
  for (int j = 0; j < 8; ++j) acc[j] = B[ob + j];

  const float* xp = x + (size_t)n * CC * TV + tv;
#pragma unroll 16
  for (int c = 0; c < CC; ++c) {
    float xc = xp[c * TV];
#pragma unroll
    for (int j = 0; j < 8; ++j)
      acc[j] = fmaf(W[(ob + j) * CC + c], xc, acc[j]);
  }

  if (p == 0) {                           // v_x -> transposed
#pragma unroll
    for (int j = 0; j < 8; ++j)
      VTb[(n * ICH + ob + j) * TV + tv] = (__bf16)acc[j];
  } else {
    if (p == 1) {                         // fold log2(e): attn uses v_exp_f32
#pragma unroll
      for (int j = 0; j < 8; ++j)
        acc[j] *= 1.4426950408889634f;
    }
    bf16x8 t;
#pragma unroll
    for (int j = 0; j < 8; ++j) t[j] = (__bf16)acc[j];
    int base = (n * TV + tv) * ICH + ob;
    if (p == 1) *(bf16x8*)(Qb + base) = t;   // k_x -> attention rows
    else        *(bf16x8*)(Kb + base) = t;   // q_x -> attention cols
  }
}

// ---------------------------------------------------------------------------
// K2: MFMA flash attention (proven r2 structure: 800 blocks, 2 m-tiles/wave,
// shared bK feeds both tiles, swapped QK^T -> packed ds_write_b64, exp2 in
// log2-domain, fused BN-stats epilogue, GSP column-major) + two micro-levers:
//  (a) V register double-buffering: pVc/pVn ping-pong like K, hiding V's
//      ~250cy L2 latency under a full chunk of compute (was loaded+used
//      within one chunk).
//  (b) s_setprio(1) around MFMA clusters: waves run barrier-free at rotated
//      chunk offsets -> scheduler favors the MFMA-issuing wave (T5 regime;
//      measured +4-7% on attn-like kernels, null only in lockstep GEMM).
// LDS 31,744 B. Grid = NB*50 = 800.
// ---------------------------------------------------------------------------
__global__ __launch_bounds__(256) void attn_kernel(
    const __bf16* __restrict__ Qb, const __bf16* __restrict__ Kb,
    const __bf16* __restrict__ VTb, __bf16* __restrict__ P,
    const float* __restrict__ Wt, const float* __restrict__ bt,
    float* __restrict__ GSP) {
  __shared__ float smem_f[7936];             // 31,744 B union arena
  int b = blockIdx.x;
  int r8 = b & 7, qq = b >> 3;               // qq in [0,100)
  int n = r8 * 2 + (qq >= 50 ? 1 : 0);
  int rowTile = (qq >= 50) ? qq - 50 : qq;
  int row0 = rowTile * 32;

  int w = threadIdx.x >> 6;
  int lane = threadIdx.x & 63;
  int m = lane & 15, q = lane >> 4;

  // main-loop Pbuf: per wave 2 tiles x 16 x 72 bf16 = 2304 elem (4608 B)
  __bf16* Pw = (__bf16*)smem_f + w * 2304;

  const __bf16* Qn = Qb  + (size_t)n * TV * ICH;
  const __bf16* Kn = Kb  + (size_t)n * TV * ICH;
  const __bf16* Vn = VTb + (size_t)n * ICH * TV;

  bf16x8 aQ0 = *(const bf16x8*)(Qn + (row0 + m) * ICH + q * 8);
  bf16x8 aQ1 = *(const bf16x8*)(Qn + (row0 + 16 + m) * ICH + q * 8);

  f32x4 o00 = {0.f,0.f,0.f,0.f}, o01 = {0.f,0.f,0.f,0.f};
  f32x4 o10 = {0.f,0.f,0.f,0.f}, o11 = {0.f,0.f,0.f,0.f};
  float ls0 = 0.f, ls1 = 0.f;                // lane-local rowsum (row = m)
  const f32x4 zero = {0.f,0.f,0.f,0.f};

  // chunk offset for this wave, rotated per block so the extra (7th) chunk
  // (offset 0) moves between waves across blocks.
  int ow = (w + b) & 3;                      // offset residue; 0 -> 7 chunks
  int nch = (ow == 0) ? 7 : 6;

  // preload chunk 0's K fragments AND V fragments into registers
  bf16x8 bKc[4], pVc[2][2];
  {
    int s0 = ow * 64;
#pragma unroll
    for (int st = 0; st < 4; ++st)
      bKc[st] = *(const bf16x8*)(Kn + (s0 + st * 16 + m) * ICH + q * 8);
#pragma unroll
    for (int kc = 0; kc < 2; ++kc)
#pragma unroll
      for (int ict = 0; ict < 2; ++ict)
        pVc[kc][ict] = *(const bf16x8*)(Vn + (ict * 16 + m) * TV + s0 + kc * 32 + q * 8);
  }

  for (int j = 0; j < nch; ++j) {
    // ---- swapped QK^T: C = P^T tile, lane (q,m): col=m (attn row),
    //      rows = s-offset st*16 + q*4 + r (4 consecutive s per lane) ----
#pragma unroll
    for (int st = 0; st < 4; ++st) {
      __builtin_amdgcn_s_setprio(1);
      f32x4 a0 = __builtin_amdgcn_mfma_f32_16x16x32_bf16(bKc[st], aQ0, zero, 0, 0, 0);
      f32x4 a1 = __builtin_amdgcn_mfma_f32_16x16x32_bf16(bKc[st], aQ1, zero, 0, 0, 0);
      __builtin_amdgcn_s_setprio(0);
      bf16x4 t0, t1;
#pragma unroll
      for (int r = 0; r < 4; ++r) {
        float e0 = __builtin_amdgcn_exp2f(a0[r]); ls0 += e0; t0[r] = (__bf16)e0;
        float e1 = __builtin_amdgcn_exp2f(a1[r]); ls1 += e1; t1[r] = (__bf16)e1;
      }
      int off = m * 72 + st * 16 + q * 4;    // byte off m*144+st*32+q*8: 8B-aligned
      *(bf16x4*)(Pw + off)        = t0;      // one ds_write_b64 per st/tile
      *(bf16x4*)(Pw + 1152 + off) = t1;
    }
    // prefetch NEXT chunk's K and V before the wait (both double-buffered)
    int chn = 4 * (j + 1) + ow;
    int s0n = (chn < 25 ? chn : 0) * 64;       // clamped, wave-uniform
    bf16x8 bKn[4], pVn[2][2];
#pragma unroll
    for (int st = 0; st < 4; ++st)
      bKn[st] = *(const bf16x8*)(Kn + (s0n + st * 16 + m) * ICH + q * 8);
#pragma unroll
    for (int kc = 0; kc < 2; ++kc)
#pragma unroll
      for (int ict = 0; ict < 2; ++ict)
        pVn[kc][ict] = *(const bf16x8*)(Vn + (ict * 16 + m) * TV + s0n + kc * 32 + q * 8);
    // in-wave DS write->read ordering
    asm volatile("s_waitcnt lgkmcnt(0)" ::: "memory");
    // ---- P*V: 2 k-chunks of 32 s (V from registers, loaded last chunk) ----
#pragma unroll
    for (int kc = 0; kc < 2; ++kc) {
      bf16x8 aP0 = *(const bf16x8*)(Pw + m * 72 + kc * 32 + q * 8);
      bf16x8 aP1 = *(const bf16x8*)(Pw + 1152 + m * 72 + kc * 32 + q * 8);
      __builtin_amdgcn_s_setprio(1);
      o00 = __builtin_amdgcn_mfma_f32_16x16x32_bf16(aP0, pVc[kc][0], o00, 0, 0, 0);
      o10 = __builtin_amdgcn_mfma_f32_16x16x32_bf16(aP1, pVc[kc][0], o10, 0, 0, 0);
      o01 = __builtin_amdgcn_mfma_f32_16x16x32_bf16(aP0, pVc[kc][1], o01, 0, 0, 0);
      o11 = __builtin_amdgcn_mfma_f32_16x16x32_bf16(aP1, pVc[kc][1], o11, 0, 0, 0);
      __builtin_amdgcn_s_setprio(0);
    }
#pragma unroll
    for (int st = 0; st < 4; ++st) bKc[st] = bKn[st];
#pragma unroll
    for (int kc = 0; kc < 2; ++kc)
#pragma unroll
      for (int ict = 0; ict < 2; ++ict) pVc[kc][ict] = pVn[kc][ict];
  }

  // row sums: lane (q,m) has the partial for row m over its q-subset of s;
  // sum the 4 q-lanes, then gather into the merge layout (row = q*4+r).
  ls0 += __shfl_xor(ls0, 16, 64); ls0 += __shfl_xor(ls0, 32, 64);
  ls1 += __shfl_xor(ls1, 16, 64); ls1 += __shfl_xor(ls1, 32, 64);
  f32x4 lv0, lv1;
#pragma unroll
  for (int r = 0; r < 4; ++r) {
    int src = q * 4 + r;                    // lane src (q=0 group) holds row src
    lv0[r] = __shfl(ls0, src, 64);
    lv1[r] = __shfl(ls1, src, 64);
  }

  // ---- epilogue arena (aliases Pbuf, which is dead after the barrier) ----
  float* pub = smem_f;                       // [4 waves][64 lanes][24]
  float* Pl  = smem_f + 6144;                // [32][36] normalized P tile
  float* red = smem_f + 7296;                // [4 waves][128]

  __syncthreads();
  f32x4* mp = (f32x4*)(pub + (w * 64 + lane) * 24);
  mp[0] = o00; mp[1] = o01; mp[2] = o10; mp[3] = o11;
  mp[4] = lv0; mp[5] = lv1;
  __syncthreads();

  // parallel merge: wave w owns group w; ls0 for w<2, ls1 for w>=2.
  {
    int lsIdx = 4 + (w >> 1);
    const f32x4* p0 = (const f32x4*)(pub + lane * 24);
    f32x4 osum = p0[w];
    f32x4 lsum = p0[lsIdx];
#pragma unroll
    for (int ww = 1; ww < 4; ++ww) {
      const f32x4* pp = (const f32x4*)(pub + (ww * 64 + lane) * 24);
      f32x4 ov = pp[w], lv = pp[lsIdx];
#pragma unroll
      for (int r = 0; r < 4; ++r) { osum[r] += ov[r]; lsum[r] += lv[r]; }
    }
    int tile = w >> 1, colh = (w & 1) * 16;
#pragma unroll
    for (int r = 0; r < 4; ++r) {
      float p = osum[r] / lsum[r];
      int row = tile * 16 + q * 4 + r;
      P[(n * TV + row0 + row) * ICH + colh + m] = (__bf16)p;
      Pl[row * 36 + colh + m] = p;
    }
  }
  __syncthreads();

  // ---- fused BN stats: thread (c = t&63, rows w*8..w*8+7) 64ch dot.
  // Pl reads are wave-uniform b128 broadcasts (stride 36 -> 16B-aligned).
  int c = threadIdx.x & 63;
  float wr[ICH];
#pragma unroll
  for (int i = 0; i < ICH; ++i) wr[i] = Wt[c * ICH + i];
  float bc = bt[c];
  float sy = 0.f, sy2 = 0.f;
#pragma unroll
  for (int rr = 0; rr < 8; ++rr) {
    const f32x4* pr = (const f32x4*)(Pl + (w * 8 + rr) * 36);
    float y = bc;
#pragma unroll
    for (int u = 0; u < 8; ++u) {
      f32x4 pv = pr[u];
#pragma unroll
      for (int k = 0; k < 4; ++k) y = fmaf(wr[u * 4 + k], pv[k], y);
    }
    sy += y; sy2 += y * y;
  }
  red[w * 128 + c]      = sy;
  red[w * 128 + 64 + c] = sy2;
  __syncthreads();
  if (threadIdx.x < 128) {
    int t = threadIdx.x;
    float s = red[t] + red[128 + t] + red[256 + t] + red[384 + t];
    GSP[(size_t)t * 800 + b] = s;            // COLUMN-MAJOR: consumer-contiguous
  }
}

// ---------------------------------------------------------------------------
// K3: fused finalize + apply (proven r2 version). Each block redundantly
// recomputes the 16 BN-stat column sums it needs (its 8 channels' sum-y /
// sum-y2 over the 800 GSP slots; column-major -> coalesced 64 B runs) plus
// the ChannelGate MLP, then recomputes y from bf16 P and applies BN + gate +
// residual. XCD-SWIZZLED over P tv-tiles. Grid 832 (32 no-op).
// ---------------------------------------------------------------------------
__global__ __launch_bounds__(256) void apply_kernel(
    const __bf16* __restrict__ P, const float* __restrict__ Wt,
    const float* __restrict__ bt, const float* __restrict__ GSP,
    const float* __restrict__ gamma, const float* __restrict__ beta,
    const float* __restrict__ AVG,
    const float* __restrict__ W1, const float* __restrict__ b1,
    const float* __restrict__ W2, const float* __restrict__ b2,
    const float* __restrict__ x, float* __restrict__ out) {
  int r = blockIdx.x & 7;
  int i = blockIdx.x >> 3;              // 0..103
  int cg = i & 7, h = i >> 3;           // h in 0..12
  int tb = r + 8 * h;
  if (tb >= 100) return;                // 32 no-op blocks

  int tvIdx = tb * 256 + threadIdx.x;
  int n = tvIdx / TV, tv = tvIdx % TV;

  __shared__ float sstat[16];           // [0..7]=sum y, [8..15]=sum y^2
  __shared__ float sSS[16];             // [0..7]=scale, [8..15]=shift
  __shared__ float sG[8];               // gate for (n, cg*8..cg*8+7)

  // ---- Phase A: 16 threads/column sum 50 slots each (contiguous stride-16
  // runs within a column-major GSP row of 800) ----
  {
    int colid = threadIdx.x >> 4;       // 0..15
    int sub = threadIdx.x & 15;         // 0..15
    int c8 = colid & 7;
    int gc = (colid < 8) ? (cg * 8 + c8) : (64 + cg * 8 + c8);
    const float* gp = GSP + (size_t)gc * 800;
    float s = 0.f;
#pragma unroll
    for (int k = 0; k < 50; ++k) s += gp[sub + k * 16];
#pragma unroll
    for (int off = 8; off >= 1; off >>= 1) s += __shfl_down(s, off, 16);
    if (sub == 0) sstat[colid] = s;
  }
  __syncthreads();
  if (threadIdx.x < 8) {
    int c8 = threadIdx.x;
    int c = cg * 8 + c8;
    float mean = sstat[c8] * (1.f / (float)NTV);
    float var  = sstat[8 + c8] * (1.f / (float)NTV) - mean * mean;
    float scale = rsqrtf(var + 1e-5f) * gamma[c];
    sSS[c8] = scale;
    sSS[8 + c8] = beta[c] - mean * scale;
    // ChannelGate MLP for this n (redundant across the 8 lanes, tiny)
    float hh[4];
#pragma unroll
    for (int jj = 0; jj < 4; ++jj) {
      float hv = b1[jj];
      for (int c2 = 0; c2 < CC; ++c2)
        hv = fmaf(W1[jj * CC + c2], AVG[n * CC + c2], hv);
      hh[jj] = fmaxf(hv, 0.f);
    }
    float g = b2[c];
#pragma unroll
    for (int jj = 0; jj < 4; ++jj) g = fmaf(W2[c * 4 + jj], hh[jj], g);
    sG[c8] = 1.f / (1.f + __expf(-g));
  }
  __syncthreads();

  // ---- Phase B: recompute y for 8 channels from bf16 P, apply ----
  float f[ICH];
  const bf16x8* pp = (const bf16x8*)(P + ((size_t)(n * TV + tv)) * ICH);
#pragma unroll
  for (int u = 0; u < 4; ++u) {
    bf16x8 v = pp[u];
#pragma unroll
    for (int j = 0; j < 8; ++j) f[u * 8 + j] = (float)v[j];
  }

#pragma unroll
  for (int j = 0; j < 8; ++j) {
    int c = cg * 8 + j;
    float y = bt[c];
#pragma unroll
    for (int ii = 0; ii < ICH; ++ii) y = fmaf(Wt[c * ICH + ii], f[ii], y);
    size_t idx = ((size_t)(n * CC + c)) * TV + tv;
    out[idx] = sG[j] * fmaf(y, sSS[j], sSS[8 + j]) + x[idx];
  }
}

// ---------------------------------------------------------------------------
extern "C" void kernel_launch(void* const* d_in, const int* in_sizes, int n_in,
                              void* d_out, int out_size, void* d_ws, size_t ws_size,
                              hipStream_t stream) {
  const float* x     = (const float*)d_in[0];
  const float* Wv    = (const float*)d_in[1];
  const float* bv    = (const float*)d_in[2];
  const float* Wk    = (const float*)d_in[3];
  const float* bk    = (const float*)d_in[4];
  const float* Wq    = (const float*)d_in[5];
  const float* bq    = (const float*)d_in[6];
  const float* Wt    = (const float*)d_in[7];
  const float* bt    = (const float*)d_in[8];
  const float* gamma = (const float*)d_in[9];
  const float* beta  = (const float*)d_in[10];
  const float* W1    = (const float*)d_in[11];
  const float* b1    = (const float*)d_in[12];
  const float* W2    = (const float*)d_in[13];
  const float* b2    = (const float*)d_in[14];
  float* out = (float*)d_out;
  char* ws = (char*)d_ws;

  // workspace layout (bytes) — total ~7.0 MB
  const size_t E = 819200;                    // N*TV*ICH elements
  __bf16* Qb  = (__bf16*)(ws);                // 2E bytes
  __bf16* Kb  = (__bf16*)(ws + 2*E);          // 2E bytes
  __bf16* VTb = (__bf16*)(ws + 4*E);          // 2E bytes
  __bf16* Pb  = (__bf16*)(ws + 6*E);          // 2E bytes
  float*  GSP = (float*) (ws + 8*E);          // 409600 B column-major partials
  float*  AVG = (float*) (ws + 8*E + 409600); // 4096 B (NB*CC)

  proj_gate_kernel<<<1312, 256, 0, stream>>>(x, Wv, bv, Wk, bk, Wq, bq,
                                             Qb, Kb, VTb, AVG);
  attn_kernel<<<NB * 50, 256, 0, stream>>>(Qb, Kb, VTb, Pb, Wt, bt, GSP);
  apply_kernel<<<832, 256, 0, stream>>>(Pb, Wt, bt, GSP, gamma, beta, AVG,
                                        W1, b1, W2, b2, x, out);
}

// Round 11
// 136.773 us; speedup vs baseline: 4.6839x; 1.0142x over previous
//
#include <hip/hip_runtime.h>
#include <hip/hip_bf16.h>
#include <math.h>

// Problem constants
#define NB   16      // batch
#define CC   64      // channels
#define ICH  32      // inter channels
#define TV   1600    // T*V = 64*25
#define NTV  (NB*TV) // 25600

typedef __bf16 bf16x8 __attribute__((ext_vector_type(8)));
typedef __bf16 bf16x4 __attribute__((ext_vector_type(4)));
typedef float  f32x4  __attribute__((ext_vector_type(4)));

// ---------------------------------------------------------------------------
// K1: 1x1 conv projections, p-split (12-way: 3 proj x 4 o-groups), XCD-
// SWIZZLED so all 12 blocks sharing an x-tile land on ONE XCD residue class.
// Proj blocks 0..1247 (48 no-op), gate blocks 1248..1311.
//  Qb = k_x [N,TV,32] (PRE-SCALED by log2e -> attn uses v_exp_f32 directly)
//  Kb = q_x [N,TV,32]   VTb = v_x^T [N,32,TV]   AVG -> workspace
// ---------------------------------------------------------------------------
__global__ __launch_bounds__(256) void proj_gate_kernel(
    const float* __restrict__ x,
    const float* __restrict__ Wv, const float* __restrict__ bv,
    const float* __restrict__ Wk, const float* __restrict__ bk,
    const float* __restrict__ Wq, const float* __restrict__ bq,
    __bf16* __restrict__ Qb, __bf16* __restrict__ Kb,
    __bf16* __restrict__ VTb, float* __restrict__ AVG) {
  if (blockIdx.x >= 1248) {
    // ---- ChannelGate phase 1: per-(n, c) mean over TV ----
    int b = blockIdx.x - 1248;
    int n = b >> 2, cq = b & 3;
    int c16 = threadIdx.x >> 4, l = threadIdx.x & 15;
    int c = cq * 16 + c16;
    const float4* xp = (const float4*)(x + ((size_t)n * CC + c) * TV) + l;
    float s = 0.f;
#pragma unroll
    for (int i = 0; i < 25; ++i) {
      float4 v = xp[i * 16];
      s += v.x + v.y + v.z + v.w;
    }
#pragma unroll
    for (int off = 8; off >= 1; off >>= 1) s += __shfl_down(s, off, 16);
    if (l == 0) AVG[n * CC + c] = s * (1.0f / (float)TV);
    return;
  }

  // XCD swizzle: XCD = blockIdx % 8; tile = r + 8g so all subs of a tile
  // share residue r -> same XCD.
  int r = blockIdx.x & 7;
  int i = blockIdx.x >> 3;               // 0..155
  int g = i / 12, sub = i % 12;          // sub = p*4 + og
  int tile = r + 8 * g;
  if (tile >= 100) return;               // 48 no-op blocks

  int p = sub >> 2, og = sub & 3;
  int ob = og * 8;
  int tvIdx = tile * 256 + threadIdx.x;  // 0..25599
  int n = tvIdx / TV, tv = tvIdx % TV;

  const float* W; const float* B;
  if (p == 0)      { W = Wv; B = bv; }
  else if (p == 1) { W = Wk; B = bk; }
  else             { W = Wq; B = bq; }

  float acc[8];
#pragma unroll
  for (int j = 0; j < 8; ++j) acc[j] = B[ob + j];

  const float* xp = x + (size_t)n * CC * TV + tv;
#pragma unroll 16
  for (int c = 0; c < CC; ++c) {
    float xc = xp[c * TV];
#pragma unroll
    for (int j = 0; j < 8; ++j)
      acc[j] = fmaf(W[(ob + j) * CC + c], xc, acc[j]);
  }

  if (p == 0) {                           // v_x -> transposed
#pragma unroll
    for (int j = 0; j < 8; ++j)
      VTb[(n * ICH + ob + j) * TV + tv] = (__bf16)acc[j];
  } else {
    if (p == 1) {                         // fold log2(e): attn uses v_exp_f32
#pragma unroll
      for (int j = 0; j < 8; ++j)
        acc[j] *= 1.4426950408889634f;
    }
    bf16x8 t;
#pragma unroll
    for (int j = 0; j < 8; ++j) t[j] = (__bf16)acc[j];
    int base = (n * TV + tv) * ICH + ob;
    if (p == 1) *(bf16x8*)(Qb + base) = t;   // k_x -> attention rows
    else        *(bf16x8*)(Kb + base) = t;   // q_x -> attention cols
  }
}

// ---------------------------------------------------------------------------
// K2: MFMA flash attention -- r2 structure (800 blocks, 2 m-tiles/wave,
// swapped QK^T -> packed ds_write_b64, exp2 log2-domain, fused BN epilogue)
// + DEPTH-2 SOFTWARE PIPELINE on the P buffer: Pw double-buffered; each
// iteration reads P(j) fragments EARLY, then computes QK(j+1)+exp+writes to
// the other buffer (~350cy that hide the ds_read latency), then does PV(j)
// with zero exposed LDS turnaround. K loads reuse the dead bKc regs; V(j+1)
// loads issue after PV(j) (full-QK prefetch distance). No setprio (r10 A/B:
// neutral). LDS 36,864 B -> 4 blocks/CU. Grid = NB*50 = 800.
// ---------------------------------------------------------------------------
__global__ __launch_bounds__(256) void attn_kernel(
    const __bf16* __restrict__ Qb, const __bf16* __restrict__ Kb,
    const __bf16* __restrict__ VTb, __bf16* __restrict__ P,
    const float* __restrict__ Wt, const float* __restrict__ bt,
    float* __restrict__ GSP) {
  __shared__ float smem_f[9216];             // 36,864 B arena (dbuf + epilogue)
  int b = blockIdx.x;
  int r8 = b & 7, qq = b >> 3;               // qq in [0,100)
  int n = r8 * 2 + (qq >= 50 ? 1 : 0);
  int rowTile = (qq >= 50) ? qq - 50 : qq;
  int row0 = rowTile * 32;

  int w = threadIdx.x >> 6;
  int lane = threadIdx.x & 63;
  int m = lane & 15, q = lane >> 4;

  // double-buffered Pbuf: per wave 2 x (2 tiles x 16 x 72 bf16) = 9216 B
  __bf16* Pw0 = (__bf16*)smem_f + w * 4608;
  __bf16* Pw1 = Pw0 + 2304;

  const __bf16* Qn = Qb  + (size_t)n * TV * ICH;
  const __bf16* Kn = Kb  + (size_t)n * TV * ICH;
  const __bf16* Vn = VTb + (size_t)n * ICH * TV;

  bf16x8 aQ0 = *(const bf16x8*)(Qn + (row0 + m) * ICH + q * 8);
  bf16x8 aQ1 = *(const bf16x8*)(Qn + (row0 + 16 + m) * ICH + q * 8);

  f32x4 o00 = {0.f,0.f,0.f,0.f}, o01 = {0.f,0.f,0.f,0.f};
  f32x4 o10 = {0.f,0.f,0.f,0.f}, o11 = {0.f,0.f,0.f,0.f};
  float ls0 = 0.f, ls1 = 0.f;                // lane-local rowsum (row = m)
  const f32x4 zero = {0.f,0.f,0.f,0.f};

  // chunk offset for this wave, rotated per block so the extra (7th) chunk
  // (offset 0) moves between waves across blocks.
  int ow = (w + b) & 3;                      // offset residue; 0 -> 7 chunks
  int nch = (ow == 0) ? 7 : 6;

  bf16x8 bKc[4], pVc[2][2];

  // ---- prologue: K(0) -> QK(0)+exp -> buf0; then K(1), V(0) ----
  {
    int s0 = ow * 64;
#pragma unroll
    for (int st = 0; st < 4; ++st)
      bKc[st] = *(const bf16x8*)(Kn + (s0 + st * 16 + m) * ICH + q * 8);
#pragma unroll
    for (int st = 0; st < 4; ++st) {
      f32x4 a0 = __builtin_amdgcn_mfma_f32_16x16x32_bf16(bKc[st], aQ0, zero, 0, 0, 0);
      f32x4 a1 = __builtin_amdgcn_mfma_f32_16x16x32_bf16(bKc[st], aQ1, zero, 0, 0, 0);
      bf16x4 t0, t1;
#pragma unroll
      for (int r = 0; r < 4; ++r) {
        float e0 = __builtin_amdgcn_exp2f(a0[r]); ls0 += e0; t0[r] = (__bf16)e0;
        float e1 = __builtin_amdgcn_exp2f(a1[r]); ls1 += e1; t1[r] = (__bf16)e1;
      }
      int off = m * 72 + st * 16 + q * 4;    // 8B-aligned ds_write_b64
      *(bf16x4*)(Pw0 + off)        = t0;
      *(bf16x4*)(Pw0 + 1152 + off) = t1;
    }
    int c1 = (4 + ow) * 64;                  // chunk 1 (nch >= 6 always)
#pragma unroll
    for (int st = 0; st < 4; ++st)
      bKc[st] = *(const bf16x8*)(Kn + (c1 + st * 16 + m) * ICH + q * 8);
#pragma unroll
    for (int kc = 0; kc < 2; ++kc)
#pragma unroll
      for (int ict = 0; ict < 2; ++ict)
        pVc[kc][ict] = *(const bf16x8*)(Vn + (ict * 16 + m) * TV + s0 + kc * 32 + q * 8);
  }

  // ---- pipelined main loop: invariants at iteration j entry:
  //   buf[j&1] = P(j) (writes issued one stage ago); bKc = K(j+1); pVc = V(j)
  for (int j = 0; j < nch; ++j) {
    __bf16* rbuf = (j & 1) ? Pw1 : Pw0;
    __bf16* wbuf = (j & 1) ? Pw0 : Pw1;
    // drain P(j) writes (a full stage old -> near-free)
    asm volatile("s_waitcnt lgkmcnt(0)" ::: "memory");
    // EARLY P(j) fragment reads: latency hides under QK(j+1)
    bf16x8 aP00 = *(const bf16x8*)(rbuf + m * 72 +      q * 8);
    bf16x8 aP01 = *(const bf16x8*)(rbuf + m * 72 + 32 + q * 8);
    bf16x8 aP10 = *(const bf16x8*)(rbuf + 1152 + m * 72 +      q * 8);
    bf16x8 aP11 = *(const bf16x8*)(rbuf + 1152 + m * 72 + 32 + q * 8);
    // QK(j+1)+exp -> writes to the OTHER buffer (skipped on last chunk)
    if (j + 1 < nch) {
#pragma unroll
      for (int st = 0; st < 4; ++st) {
        f32x4 a0 = __builtin_amdgcn_mfma_f32_16x16x32_bf16(bKc[st], aQ0, zero, 0, 0, 0);
        f32x4 a1 = __builtin_amdgcn_mfma_f32_16x16x32_bf16(bKc[st], aQ1, zero, 0, 0, 0);
        bf16x4 t0, t1;
#pragma unroll
        for (int r = 0; r < 4; ++r) {
          float e0 = __builtin_amdgcn_exp2f(a0[r]); ls0 += e0; t0[r] = (__bf16)e0;
          float e1 = __builtin_amdgcn_exp2f(a1[r]); ls1 += e1; t1[r] = (__bf16)e1;
        }
        int off = m * 72 + st * 16 + q * 4;
        *(bf16x4*)(wbuf + off)        = t0;
        *(bf16x4*)(wbuf + 1152 + off) = t1;
      }
    }
    // prefetch K(j+2) into bKc (dead after QK above); clamped wave-uniform
    {
      int chn = 4 * (j + 2) + ow;
      int s0n = (chn < 25 ? chn : 0) * 64;
#pragma unroll
      for (int st = 0; st < 4; ++st)
        bKc[st] = *(const bf16x8*)(Kn + (s0n + st * 16 + m) * ICH + q * 8);
    }
    // PV(j): aP reads retired long ago (counted lgkm wait is ~free)
    o00 = __builtin_amdgcn_mfma_f32_16x16x32_bf16(aP00, pVc[0][0], o00, 0, 0, 0);
    o10 = __builtin_amdgcn_mfma_f32_16x16x32_bf16(aP10, pVc[0][0], o10, 0, 0, 0);
    o01 = __builtin_amdgcn_mfma_f32_16x16x32_bf16(aP00, pVc[0][1], o01, 0, 0, 0);
    o11 = __builtin_amdgcn_mfma_f32_16x16x32_bf16(aP10, pVc[0][1], o11, 0, 0, 0);
    o00 = __builtin_amdgcn_mfma_f32_16x16x32_bf16(aP01, pVc[1][0], o00, 0, 0, 0);
    o10 = __builtin_amdgcn_mfma_f32_16x16x32_bf16(aP11, pVc[1][0], o10, 0, 0, 0);
    o01 = __builtin_amdgcn_mfma_f32_16x16x32_bf16(aP01, pVc[1][1], o01, 0, 0, 0);
    o11 = __builtin_amdgcn_mfma_f32_16x16x32_bf16(aP11, pVc[1][1], o11, 0, 0, 0);
    // prefetch V(j+1) into pVc (issues after the MFMAs read pVc: WAR-safe;
    // a full QK phase of distance before next use)
    {
      int chv = 4 * (j + 1) + ow;
      int s0v = (chv < 25 ? chv : 0) * 64;
#pragma unroll
      for (int kc = 0; kc < 2; ++kc)
#pragma unroll
        for (int ict = 0; ict < 2; ++ict)
          pVc[kc][ict] = *(const bf16x8*)(Vn + (ict * 16 + m) * TV + s0v + kc * 32 + q * 8);
    }
  }

  // row sums: lane (q,m) has the partial for row m over its q-subset of s;
  // sum the 4 q-lanes, then gather into the merge layout (row = q*4+r).
  ls0 += __shfl_xor(ls0, 16, 64); ls0 += __shfl_xor(ls0, 32, 64);
  ls1 += __shfl_xor(ls1, 16, 64); ls1 += __shfl_xor(ls1, 32, 64);
  f32x4 lv0, lv1;
#pragma unroll
  for (int r = 0; r < 4; ++r) {
    int src = q * 4 + r;                    // lane src (q=0 group) holds row src
    lv0[r] = __shfl(ls0, src, 64);
    lv1[r] = __shfl(ls1, src, 64);
  }

  // ---- epilogue arena (aliases Pbuf, which is dead after the barrier) ----
  float* pub = smem_f;                       // [4 waves][64 lanes][24]
  float* Pl  = smem_f + 6144;                // [32][36] normalized P tile
  float* red = smem_f + 7296;                // [4 waves][128]

  __syncthreads();
  f32x4* mp = (f32x4*)(pub + (w * 64 + lane) * 24);
  mp[0] = o00; mp[1] = o01; mp[2] = o10; mp[3] = o11;
  mp[4] = lv0; mp[5] = lv1;
  __syncthreads();

  // parallel merge: wave w owns group w; ls0 for w<2, ls1 for w>=2.
  {
    int lsIdx = 4 + (w >> 1);
    const f32x4* p0 = (const f32x4*)(pub + lane * 24);
    f32x4 osum = p0[w];
    f32x4 lsum = p0[lsIdx];
#pragma unroll
    for (int ww = 1; ww < 4; ++ww) {
      const f32x4* pp = (const f32x4*)(pub + (ww * 64 + lane) * 24);
      f32x4 ov = pp[w], lv = pp[lsIdx];
#pragma unroll
      for (int r = 0; r < 4; ++r) { osum[r] += ov[r]; lsum[r] += lv[r]; }
    }
    int tile = w >> 1, colh = (w & 1) * 16;
#pragma unroll
    for (int r = 0; r < 4; ++r) {
      float p = osum[r] / lsum[r];
      int row = tile * 16 + q * 4 + r;
      P[(n * TV + row0 + row) * ICH + colh + m] = (__bf16)p;
      Pl[row * 36 + colh + m] = p;
    }
  }
  __syncthreads();

  // ---- fused BN stats: thread (c = t&63, rows w*8..w*8+7) 64ch dot.
  // Pl reads are wave-uniform b128 broadcasts (stride 36 -> 16B-aligned).
  int c = threadIdx.x & 63;
  float wr[ICH];
#pragma unroll
  for (int i = 0; i < ICH; ++i) wr[i] = Wt[c * ICH + i];
  float bc = bt[c];
  float sy = 0.f, sy2 = 0.f;
#pragma unroll
  for (int rr = 0; rr < 8; ++rr) {
    const f32x4* pr = (const f32x4*)(Pl + (w * 8 + rr) * 36);
    float y = bc;
#pragma unroll
    for (int u = 0; u < 8; ++u) {
      f32x4 pv = pr[u];
#pragma unroll
      for (int k = 0; k < 4; ++k) y = fmaf(wr[u * 4 + k], pv[k], y);
    }
    sy += y; sy2 += y * y;
  }
  red[w * 128 + c]      = sy;
  red[w * 128 + 64 + c] = sy2;
  __syncthreads();
  if (threadIdx.x < 128) {
    int t = threadIdx.x;
    float s = red[t] + red[128 + t] + red[256 + t] + red[384 + t];
    GSP[(size_t)t * 800 + b] = s;            // COLUMN-MAJOR: consumer-contiguous
  }
}

// ---------------------------------------------------------------------------
// K3: fused finalize + apply (proven r2 version). Each block redundantly
// recomputes the 16 BN-stat column sums it needs (its 8 channels' sum-y /
// sum-y2 over the 800 GSP slots; column-major -> coalesced 64 B runs) plus
// the ChannelGate MLP, then recomputes y from bf16 P and applies BN + gate +
// residual. XCD-SWIZZLED over P tv-tiles. Grid 832 (32 no-op).
// ---------------------------------------------------------------------------
__global__ __launch_bounds__(256) void apply_kernel(
    const __bf16* __restrict__ P, const float* __restrict__ Wt,
    const float* __restrict__ bt, const float* __restrict__ GSP,
    const float* __restrict__ gamma, const float* __restrict__ beta,
    const float* __restrict__ AVG,
    const float* __restrict__ W1, const float* __restrict__ b1,
    const float* __restrict__ W2, const float* __restrict__ b2,
    const float* __restrict__ x, float* __restrict__ out) {
  int r = blockIdx.x & 7;
  int i = blockIdx.x >> 3;              // 0..103
  int cg = i & 7, h = i >> 3;           // h in 0..12
  int tb = r + 8 * h;
  if (tb >= 100) return;                // 32 no-op blocks

  int tvIdx = tb * 256 + threadIdx.x;
  int n = tvIdx / TV, tv = tvIdx % TV;

  __shared__ float sstat[16];           // [0..7]=sum y, [8..15]=sum y^2
  __shared__ float sSS[16];             // [0..7]=scale, [8..15]=shift
  __shared__ float sG[8];               // gate for (n, cg*8..cg*8+7)

  // ---- Phase A: 16 threads/column sum 50 slots each (contiguous stride-16
  // runs within a column-major GSP row of 800) ----
  {
    int colid = threadIdx.x >> 4;       // 0..15
    int sub = threadIdx.x & 15;         // 0..15
    int c8 = colid & 7;
    int gc = (colid < 8) ? (cg * 8 + c8) : (64 + cg * 8 + c8);
    const float* gp = GSP + (size_t)gc * 800;
    float s = 0.f;
#pragma unroll
    for (int k = 0; k < 50; ++k) s += gp[sub + k * 16];
#pragma unroll
    for (int off = 8; off >= 1; off >>= 1) s += __shfl_down(s, off, 16);
    if (sub == 0) sstat[colid] = s;
  }
  __syncthreads();
  if (threadIdx.x < 8) {
    int c8 = threadIdx.x;
    int c = cg * 8 + c8;
    float mean = sstat[c8] * (1.f / (float)NTV);
    float var  = sstat[8 + c8] * (1.f / (float)NTV) - mean * mean;
    float scale = rsqrtf(var + 1e-5f) * gamma[c];
    sSS[c8] = scale;
    sSS[8 + c8] = beta[c] - mean * scale;
    // ChannelGate MLP for this n (redundant across the 8 lanes, tiny)
    float hh[4];
#pragma unroll
    for (int jj = 0; jj < 4; ++jj) {
      float hv = b1[jj];
      for (int c2 = 0; c2 < CC; ++c2)
        hv = fmaf(W1[jj * CC + c2], AVG[n * CC + c2], hv);
      hh[jj] = fmaxf(hv, 0.f);
    }
    float g = b2[c];
#pragma unroll
    for (int jj = 0; jj < 4; ++jj) g = fmaf(W2[c * 4 + jj], hh[jj], g);
    sG[c8] = 1.f / (1.f + __expf(-g));
  }
  __syncthreads();

  // ---- Phase B: recompute y for 8 channels from bf16 P, apply ----
  float f[ICH];
  const bf16x8* pp = (const bf16x8*)(P + ((size_t)(n * TV + tv)) * ICH);
#pragma unroll
  for (int u = 0; u < 4; ++u) {
    bf16x8 v = pp[u];
#pragma unroll
    for (int j = 0; j < 8; ++j) f[u * 8 + j] = (float)v[j];
  }

#pragma unroll
  for (int j = 0; j < 8; ++j) {
    int c = cg * 8 + j;
    float y = bt[c];
#pragma unroll
    for (int ii = 0; ii < ICH; ++ii) y = fmaf(Wt[c * ICH + ii], f[ii], y);
    size_t idx = ((size_t)(n * CC + c)) * TV + tv;
    out[idx] = sG[j] * fmaf(y, sSS[j], sSS[8 + j]) + x[idx];
  }
}

// ---------------------------------------------------------------------------
extern "C" void kernel_launch(void* const* d_in, const int* in_sizes, int n_in,
                              void* d_out, int out_size, void* d_ws, size_t ws_size,
                              hipStream_t stream) {
  const float* x     = (const float*)d_in[0];
  const float* Wv    = (const float*)d_in[1];
  const float* bv    = (const float*)d_in[2];
  const float* Wk    = (const float*)d_in[3];
  const float* bk    = (const float*)d_in[4];
  const float* Wq    = (const float*)d_in[5];
  const float* bq    = (const float*)d_in[6];
  const float* Wt    = (const float*)d_in[7];
  const float* bt    = (const float*)d_in[8];
  const float* gamma = (const float*)d_in[9];
  const float* beta  = (const float*)d_in[10];
  const float* W1    = (const float*)d_in[11];
  const float* b1    = (const float*)d_in[12];
  const float* W2    = (const float*)d_in[13];
  const float* b2    = (const float*)d_in[14];
  float* out = (float*)d_out;
  char* ws = (char*)d_ws;

  // workspace layout (bytes) — total ~7.0 MB
  const size_t E = 819200;                    // N*TV*ICH elements
  __bf16* Qb  = (__bf16*)(ws);                // 2E bytes
  __bf16* Kb  = (__bf16*)(ws + 2*E);          // 2E bytes
  __bf16* VTb = (__bf16*)(ws + 4*E);          // 2E bytes
  __bf16* Pb  = (__bf16*)(ws + 6*E);          // 2E bytes
  float*  GSP = (float*) (ws + 8*E);          // 409600 B column-major partials
  float*  AVG = (float*) (ws + 8*E + 409600); // 4096 B (NB*CC)

  proj_gate_kernel<<<1312, 256, 0, stream>>>(x, Wv, bv, Wk, bk, Wq, bq,
                                             Qb, Kb, VTb, AVG);
  attn_kernel<<<NB * 50, 256, 0, stream>>>(Qb, Kb, VTb, Pb, Wt, bt, GSP);
  apply_kernel<<<832, 256, 0, stream>>>(Pb, Wt, bt, GSP, gamma, beta, AVG,
                                        W1, b1, W2, b2, x, out);
}